// Round 1
// baseline (4396.226 us; speedup 1.0000x reference)
//
#include <hip/hip_runtime.h>
#include <math.h>

#define Bb 8
#define Ss 2048
#define Ee 256
#define Hh 4
#define Dd 64

// ---------------- embedding gather ----------------
__global__ __launch_bounds__(256) void k_gather(const int* __restrict__ seqs,
                                                const float* __restrict__ emb,
                                                float* __restrict__ x) {
  int idx = blockIdx.x * 256 + threadIdx.x;   // over B*S*64 float4s
  int row = idx >> 6, c4 = idx & 63;
  int tok = seqs[row];
  reinterpret_cast<float4*>(x)[(size_t)row * 64 + c4] =
      reinterpret_cast<const float4*>(emb)[(size_t)tok * 64 + c4];
}

// ---------------- fused Q/K/V projection (relu(x@W^T + b)) ----------------
// grid (12, 256): bn selects {q,k,v} x 4 col-tiles, bm tiles 16384 rows.
__global__ __launch_bounds__(256) void k_qkv(const float* __restrict__ x,
    const float* __restrict__ Wq, const float* __restrict__ Wk, const float* __restrict__ Wv,
    const float* __restrict__ bq, const float* __restrict__ bk, const float* __restrict__ bv,
    float* __restrict__ Qf, float* __restrict__ Kf, float* __restrict__ Vf, int mod) {
  __shared__ float As[16][65];
  __shared__ float Bs[16][65];
  int tid = threadIdx.x;
  int bn = blockIdx.x, bm = blockIdx.y;
  int w = bn >> 2;                 // 0=q 1=k 2=v
  int ctile = (bn & 3) << 6;       // column offset within 256
  const float* W = (w == 0 ? Wq : (w == 1 ? Wk : Wv)) + (size_t)mod * Hh * Dd * Ee;
  const float* bias = (w == 0 ? bq : (w == 1 ? bk : bv)) + mod * Hh * Dd;
  float* Out = (w == 0 ? Qf : (w == 1 ? Kf : Vf));
  int m0 = (tid >> 4) << 2, n0 = (tid & 15) << 2;
  int lr = tid >> 2, lk = (tid & 3) << 2;
  float acc[4][4] = {};
  for (int k0 = 0; k0 < Ee; k0 += 16) {
    float4 a = *reinterpret_cast<const float4*>(x + (size_t)(bm * 64 + lr) * Ee + k0 + lk);
    float4 b = *reinterpret_cast<const float4*>(W + (size_t)(ctile + lr) * Ee + k0 + lk);
    As[lk + 0][lr] = a.x; As[lk + 1][lr] = a.y; As[lk + 2][lr] = a.z; As[lk + 3][lr] = a.w;
    Bs[lk + 0][lr] = b.x; Bs[lk + 1][lr] = b.y; Bs[lk + 2][lr] = b.z; Bs[lk + 3][lr] = b.w;
    __syncthreads();
#pragma unroll
    for (int kk = 0; kk < 16; kk++) {
      float av[4], bv2[4];
#pragma unroll
      for (int i = 0; i < 4; i++) { av[i] = As[kk][m0 + i]; bv2[i] = Bs[kk][n0 + i]; }
#pragma unroll
      for (int i = 0; i < 4; i++)
#pragma unroll
        for (int j = 0; j < 4; j++) acc[i][j] = fmaf(av[i], bv2[j], acc[i][j]);
    }
    __syncthreads();
  }
#pragma unroll
  for (int i = 0; i < 4; i++) {
    int gm = bm * 64 + m0 + i;
#pragma unroll
    for (int j = 0; j < 4; j++) {
      int c = ctile + n0 + j;
      float v = acc[i][j] + bias[c];
      Out[(size_t)gm * Ee + c] = v > 0.f ? v : 0.f;
    }
  }
}

// ---------------- scores: S[s,t] = (Q·K)/16 per (b,h) ----------------
// grid (32, 32, nb*4): x→t tile, y→s tile, z→(b_local,h)
__global__ __launch_bounds__(256) void k_scores(const float* __restrict__ Qf,
    const float* __restrict__ Kf, float* __restrict__ Sc, int bStart) {
  __shared__ float As[64][65];
  __shared__ float Bs[64][65];
  int tid = threadIdx.x;
  int z = blockIdx.z;
  int b = bStart + (z >> 2), h = z & 3;
  const float* Qb = Qf + (size_t)b * Ss * Ee + h * Dd;
  const float* Kb = Kf + (size_t)b * Ss * Ee + h * Dd;
  float* S = Sc + (size_t)z * Ss * Ss;
  int lr = tid >> 2, lk = (tid & 3) << 4;
  int s0 = blockIdx.y * 64, t0 = blockIdx.x * 64;
#pragma unroll
  for (int q = 0; q < 4; q++) {
    float4 a = *reinterpret_cast<const float4*>(Qb + (size_t)(s0 + lr) * Ee + lk + q * 4);
    float4 k = *reinterpret_cast<const float4*>(Kb + (size_t)(t0 + lr) * Ee + lk + q * 4);
    As[lr][lk + q * 4 + 0] = a.x; As[lr][lk + q * 4 + 1] = a.y;
    As[lr][lk + q * 4 + 2] = a.z; As[lr][lk + q * 4 + 3] = a.w;
    Bs[lr][lk + q * 4 + 0] = k.x; Bs[lr][lk + q * 4 + 1] = k.y;
    Bs[lr][lk + q * 4 + 2] = k.z; Bs[lr][lk + q * 4 + 3] = k.w;
  }
  __syncthreads();
  int m0 = (tid >> 4) << 2, n0 = (tid & 15) << 2;
  float acc[4][4] = {};
  for (int kk = 0; kk < 64; kk++) {
    float av[4], bv[4];
#pragma unroll
    for (int i = 0; i < 4; i++) { av[i] = As[m0 + i][kk]; bv[i] = Bs[n0 + i][kk]; }
#pragma unroll
    for (int i = 0; i < 4; i++)
#pragma unroll
      for (int j = 0; j < 4; j++) acc[i][j] = fmaf(av[i], bv[j], acc[i][j]);
  }
#pragma unroll
  for (int i = 0; i < 4; i++)
#pragma unroll
    for (int j = 0; j < 4; j++)
      S[(size_t)(s0 + m0 + i) * Ss + t0 + n0 + j] = acc[i][j] * (1.f / 16.f);
}

// ---------------- column softmax (axis=2, over s) in place ----------------
// one thread per (z,t); adjacent threads -> adjacent columns (coalesced)
__global__ __launch_bounds__(256) void k_colsm(float* __restrict__ Sc) {
  int idx = blockIdx.x * 256 + threadIdx.x;
  int z = idx >> 11, t = idx & 2047;
  float* S = Sc + (size_t)z * Ss * Ss + t;
  float m = -1e30f, l = 0.f;
  for (int s = 0; s < Ss; s++) {
    float v = S[(size_t)s * Ss];
    float nm = fmaxf(m, v);
    l = l * __expf(m - nm) + __expf(v - nm);
    m = nm;
  }
  float inv = 1.f / l;
  for (int s = 0; s < Ss; s++) {
    float v = S[(size_t)s * Ss];
    S[(size_t)s * Ss] = __expf(v - m) * inv;
  }
}

// ---------------- row stats (axis=3 softmax max/sum), wave per row ----------------
__global__ __launch_bounds__(256) void k_rowstat(const float* __restrict__ Sc,
    float* __restrict__ rm, float* __restrict__ rl, int bStart) {
  int wid = (blockIdx.x << 2) + (threadIdx.x >> 6);
  int lane = threadIdx.x & 63;
  int z = wid >> 11, s = wid & 2047;
  const float* row = Sc + (size_t)z * Ss * Ss + (size_t)s * Ss;
  float m = -1e30f, l = 0.f;
  for (int t = lane; t < Ss; t += 64) {
    float v = row[t];
    float nm = fmaxf(m, v);
    l = l * __expf(m - nm) + __expf(v - nm);
    m = nm;
  }
#pragma unroll
  for (int off = 32; off; off >>= 1) {
    float mo = __shfl_xor(m, off);
    float lo = __shfl_xor(l, off);
    float nm = fmaxf(m, mo);
    l = l * __expf(m - nm) + lo * __expf(mo - nm);
    m = nm;
  }
  if (lane == 0) {
    int gz = bStart * Hh + z;
    rm[(size_t)gz * Ss + s] = m;
    rl[(size_t)gz * Ss + s] = l;
  }
}

// ---------------- A@V with fused row softmax; writes Zall [bs][h*64+d] ----------------
// grid (32, nb*4): x→s tile, y→(b_local,h)
__global__ __launch_bounds__(256) void k_av(const float* __restrict__ Sc,
    const float* __restrict__ Vf, const float* __restrict__ rm, const float* __restrict__ rl,
    float* __restrict__ Zall, int bStart) {
  __shared__ float As[64][65];
  __shared__ float Bs[64][65];
  int tid = threadIdx.x;
  int z = blockIdx.y;
  int b = bStart + (z >> 2), h = z & 3;
  const float* A = Sc + (size_t)z * Ss * Ss;
  const float* Vb = Vf + (size_t)b * Ss * Ee + h * Dd;
  int gz = bStart * Hh + z;
  const float* rmz = rm + (size_t)gz * Ss;
  const float* rlz = rl + (size_t)gz * Ss;
  int s0 = blockIdx.x * 64;
  int lr = tid >> 2, lk = (tid & 3) << 4;
  float mrow = rmz[s0 + lr];
  int m0 = (tid >> 4) << 2, n0 = (tid & 15) << 2;
  float acc[4][4] = {};
  for (int k0 = 0; k0 < Ss; k0 += 64) {
#pragma unroll
    for (int q = 0; q < 4; q++) {
      float4 a = *reinterpret_cast<const float4*>(A + (size_t)(s0 + lr) * Ss + k0 + lk + q * 4);
      As[lr][lk + q * 4 + 0] = __expf(a.x - mrow);
      As[lr][lk + q * 4 + 1] = __expf(a.y - mrow);
      As[lr][lk + q * 4 + 2] = __expf(a.z - mrow);
      As[lr][lk + q * 4 + 3] = __expf(a.w - mrow);
      float4 v = *reinterpret_cast<const float4*>(Vb + (size_t)(k0 + lr) * Ee + lk + q * 4);
      Bs[lr][lk + q * 4 + 0] = v.x; Bs[lr][lk + q * 4 + 1] = v.y;
      Bs[lr][lk + q * 4 + 2] = v.z; Bs[lr][lk + q * 4 + 3] = v.w;
    }
    __syncthreads();
    for (int kk = 0; kk < 64; kk++) {
      float av[4], bv[4];
#pragma unroll
      for (int i = 0; i < 4; i++) { av[i] = As[m0 + i][kk]; bv[i] = Bs[kk][n0 + i]; }
#pragma unroll
      for (int i = 0; i < 4; i++)
#pragma unroll
        for (int j = 0; j < 4; j++) acc[i][j] = fmaf(av[i], bv[j], acc[i][j]);
    }
    __syncthreads();
  }
#pragma unroll
  for (int i = 0; i < 4; i++) {
    int s = s0 + m0 + i;
    float inv = 1.f / rlz[s];
#pragma unroll
    for (int j = 0; j < 4; j++)
      Zall[(size_t)(b * Ss + s) * Ee + h * Dd + n0 + j] = acc[i][j] * inv;
  }
}

// ---------------- ZF projection + residual: x += Zall@Wz^T + bz ----------------
// grid (4, 256)
__global__ __launch_bounds__(256) void k_zf(const float* __restrict__ Zall,
    const float* __restrict__ Wzp, const float* __restrict__ bzp,
    float* __restrict__ x, int mod) {
  __shared__ float As[16][65];
  __shared__ float Bs[16][65];
  int tid = threadIdx.x;
  int bn = blockIdx.x, bm = blockIdx.y;
  const float* W = Wzp + (size_t)mod * Ee * Ee;
  const float* bias = bzp + mod * Ee;
  int ctile = bn << 6;
  int m0 = (tid >> 4) << 2, n0 = (tid & 15) << 2;
  int lr = tid >> 2, lk = (tid & 3) << 2;
  float acc[4][4] = {};
  for (int k0 = 0; k0 < Ee; k0 += 16) {
    float4 a = *reinterpret_cast<const float4*>(Zall + (size_t)(bm * 64 + lr) * Ee + k0 + lk);
    float4 w = *reinterpret_cast<const float4*>(W + (size_t)(ctile + lr) * Ee + k0 + lk);
    As[lk + 0][lr] = a.x; As[lk + 1][lr] = a.y; As[lk + 2][lr] = a.z; As[lk + 3][lr] = a.w;
    Bs[lk + 0][lr] = w.x; Bs[lk + 1][lr] = w.y; Bs[lk + 2][lr] = w.z; Bs[lk + 3][lr] = w.w;
    __syncthreads();
#pragma unroll
    for (int kk = 0; kk < 16; kk++) {
      float av[4], bv2[4];
#pragma unroll
      for (int i = 0; i < 4; i++) { av[i] = As[kk][m0 + i]; bv2[i] = Bs[kk][n0 + i]; }
#pragma unroll
      for (int i = 0; i < 4; i++)
#pragma unroll
        for (int j = 0; j < 4; j++) acc[i][j] = fmaf(av[i], bv2[j], acc[i][j]);
    }
    __syncthreads();
  }
#pragma unroll
  for (int i = 0; i < 4; i++) {
    int gm = bm * 64 + m0 + i;
#pragma unroll
    for (int j = 0; j < 4; j++) {
      int gn = ctile + n0 + j;
      x[(size_t)gm * Ee + gn] += acc[i][j] + bias[gn];
    }
  }
}

// ---------------- final head stage 1: partial dots ----------------
// grid (64, 16, 8): chunk, label, batch
__global__ __launch_bounds__(256) void k_final1(const float* __restrict__ x,
    const float* __restrict__ Wo, float* __restrict__ part) {
  int c = blockIdx.x, l = blockIdx.y, b = blockIdx.z;
  int tid = threadIdx.x;
  const float4* xr = reinterpret_cast<const float4*>(x + (size_t)b * (Ss * Ee) + c * 8192);
  const float4* wr = reinterpret_cast<const float4*>(Wo + (size_t)l * (Ss * Ee) + c * 8192);
  float sum = 0.f;
  for (int i = tid; i < 2048; i += 256) {
    float4 a = xr[i], w = wr[i];
    sum += a.x * w.x + a.y * w.y + a.z * w.z + a.w * w.w;
  }
  __shared__ float red[256];
  red[tid] = sum;
  __syncthreads();
  for (int o = 128; o; o >>= 1) {
    if (tid < o) red[tid] += red[tid + o];
    __syncthreads();
  }
  if (tid == 0) part[((b * 16 + l) << 6) + c] = red[0];
}

__global__ void k_final2(const float* __restrict__ part, const float* __restrict__ bo,
                         float* __restrict__ out) {
  int idx = threadIdx.x;   // 128 = 8*16
  int b = idx >> 4, l = idx & 15;
  float s = 0.f;
  for (int c = 0; c < 64; c++) s += part[((b * 16 + l) << 6) + c];
  s += bo[l];
  out[idx] = 1.f / (1.f + __expf(-s));
}

extern "C" void kernel_launch(void* const* d_in, const int* in_sizes, int n_in,
                              void* d_out, int out_size, void* d_ws, size_t ws_size,
                              hipStream_t stream) {
  const int*   seqs = (const int*)d_in[0];
  const float* emb  = (const float*)d_in[1];
  const float* Wq   = (const float*)d_in[2];
  const float* bq   = (const float*)d_in[3];
  const float* Wk   = (const float*)d_in[4];
  const float* bk   = (const float*)d_in[5];
  const float* Wv   = (const float*)d_in[6];
  const float* bv   = (const float*)d_in[7];
  const float* Wz   = (const float*)d_in[8];
  const float* bz   = (const float*)d_in[9];
  const float* Wo   = (const float*)d_in[10];
  const float* bo   = (const float*)d_in[11];
  float* out = (float*)d_out;
  float* ws  = (float*)d_ws;

  float* x    = ws;                    // 4,194,304 floats
  float* Qf   = ws + 4194304;
  float* Kf   = ws + 8388608;
  float* Vf   = ws + 12582912;
  float* Zall = ws + 16777216;
  float* rm   = ws + 20971520;         // 65,536
  float* rl   = ws + 21037056;         // 65,536
  float* part = ws + 21102592;         // 8,192
  float* Sc   = ws + 21110784;
  size_t fixedBytes = (size_t)21110784 * 4;
  size_t perB = (size_t)Hh * Ss * Ss * 4;   // 67.1 MB
  int CH = 1;
  if (fixedBytes + 8 * perB <= ws_size) CH = 8;
  else if (fixedBytes + 4 * perB <= ws_size) CH = 4;
  else if (fixedBytes + 2 * perB <= ws_size) CH = 2;

  k_gather<<<(Bb * Ss * 64) / 256, 256, 0, stream>>>(seqs, emb, x);

  for (int m = 0; m < 2; m++) {
    k_qkv<<<dim3(12, 256), 256, 0, stream>>>(x, Wq, Wk, Wv, bq, bk, bv, Qf, Kf, Vf, m);
    for (int b0 = 0; b0 < Bb; b0 += CH) {
      int nb = (Bb - b0 < CH) ? (Bb - b0) : CH;
      k_scores<<<dim3(32, 32, nb * Hh), 256, 0, stream>>>(Qf, Kf, Sc, b0);
      k_colsm<<<(nb * Hh * Ss) / 256, 256, 0, stream>>>(Sc);
      k_rowstat<<<(nb * Hh * Ss) / 4, 256, 0, stream>>>(Sc, rm, rl, b0);
      k_av<<<dim3(32, nb * Hh), 256, 0, stream>>>(Sc, Vf, rm, rl, Zall, b0);
    }
    k_zf<<<dim3(4, 256), 256, 0, stream>>>(Zall, Wz, bz, x, m);
  }

  k_final1<<<dim3(64, 16, 8), 256, 0, stream>>>(x, Wo, part);
  k_final2<<<1, 128, 0, stream>>>(part, bo, out);
}

// Round 2
// 2673.717 us; speedup vs baseline: 1.6442x; 1.6442x over previous
//
#include <hip/hip_runtime.h>
#include <math.h>

#define Bb 8
#define Ss 2048
#define Ee 256
#define Hh 4
#define Dd 64

// ---------------- embedding gather ----------------
__global__ __launch_bounds__(256) void k_gather(const int* __restrict__ seqs,
                                                const float* __restrict__ emb,
                                                float* __restrict__ x) {
  int idx = blockIdx.x * 256 + threadIdx.x;   // over B*S*64 float4s
  int row = idx >> 6, c4 = idx & 63;
  int tok = seqs[row];
  reinterpret_cast<float4*>(x)[(size_t)row * 64 + c4] =
      reinterpret_cast<const float4*>(emb)[(size_t)tok * 64 + c4];
}

// ---------------- fused Q/K/V projection (relu(x@W^T + b)) ----------------
__global__ __launch_bounds__(256) void k_qkv(const float* __restrict__ x,
    const float* __restrict__ Wq, const float* __restrict__ Wk, const float* __restrict__ Wv,
    const float* __restrict__ bq, const float* __restrict__ bk, const float* __restrict__ bv,
    float* __restrict__ Qf, float* __restrict__ Kf, float* __restrict__ Vf, int mod) {
  __shared__ float As[16][65];
  __shared__ float Bs[16][65];
  int tid = threadIdx.x;
  int bn = blockIdx.x, bm = blockIdx.y;
  int w = bn >> 2;                 // 0=q 1=k 2=v
  int ctile = (bn & 3) << 6;       // column offset within 256
  const float* W = (w == 0 ? Wq : (w == 1 ? Wk : Wv)) + (size_t)mod * Hh * Dd * Ee;
  const float* bias = (w == 0 ? bq : (w == 1 ? bk : bv)) + mod * Hh * Dd;
  float* Out = (w == 0 ? Qf : (w == 1 ? Kf : Vf));
  int m0 = (tid >> 4) << 2, n0 = (tid & 15) << 2;
  int lr = tid >> 2, lk = (tid & 3) << 2;
  float acc[4][4] = {};
  for (int k0 = 0; k0 < Ee; k0 += 16) {
    float4 a = *reinterpret_cast<const float4*>(x + (size_t)(bm * 64 + lr) * Ee + k0 + lk);
    float4 b = *reinterpret_cast<const float4*>(W + (size_t)(ctile + lr) * Ee + k0 + lk);
    As[lk + 0][lr] = a.x; As[lk + 1][lr] = a.y; As[lk + 2][lr] = a.z; As[lk + 3][lr] = a.w;
    Bs[lk + 0][lr] = b.x; Bs[lk + 1][lr] = b.y; Bs[lk + 2][lr] = b.z; Bs[lk + 3][lr] = b.w;
    __syncthreads();
#pragma unroll
    for (int kk = 0; kk < 16; kk++) {
      float av[4], bv2[4];
#pragma unroll
      for (int i = 0; i < 4; i++) { av[i] = As[kk][m0 + i]; bv2[i] = Bs[kk][n0 + i]; }
#pragma unroll
      for (int i = 0; i < 4; i++)
#pragma unroll
        for (int j = 0; j < 4; j++) acc[i][j] = fmaf(av[i], bv2[j], acc[i][j]);
    }
    __syncthreads();
  }
#pragma unroll
  for (int i = 0; i < 4; i++) {
    int gm = bm * 64 + m0 + i;
#pragma unroll
    for (int j = 0; j < 4; j++) {
      int c = ctile + n0 + j;
      float v = acc[i][j] + bias[c];
      Out[(size_t)gm * Ee + c] = v > 0.f ? v : 0.f;
    }
  }
}

// ---------------- scores: S[s,t] = (Q·K)/16 per (b,h) ----------------
__global__ __launch_bounds__(256) void k_scores(const float* __restrict__ Qf,
    const float* __restrict__ Kf, float* __restrict__ Sc, int bStart) {
  __shared__ float As[64][65];
  __shared__ float Bs[64][65];
  int tid = threadIdx.x;
  int z = blockIdx.z;
  int b = bStart + (z >> 2), h = z & 3;
  const float* Qb = Qf + (size_t)b * Ss * Ee + h * Dd;
  const float* Kb = Kf + (size_t)b * Ss * Ee + h * Dd;
  float* S = Sc + (size_t)z * Ss * Ss;
  int lr = tid >> 2, lk = (tid & 3) << 4;
  int s0 = blockIdx.y * 64, t0 = blockIdx.x * 64;
#pragma unroll
  for (int q = 0; q < 4; q++) {
    float4 a = *reinterpret_cast<const float4*>(Qb + (size_t)(s0 + lr) * Ee + lk + q * 4);
    float4 k = *reinterpret_cast<const float4*>(Kb + (size_t)(t0 + lr) * Ee + lk + q * 4);
    As[lr][lk + q * 4 + 0] = a.x; As[lr][lk + q * 4 + 1] = a.y;
    As[lr][lk + q * 4 + 2] = a.z; As[lr][lk + q * 4 + 3] = a.w;
    Bs[lr][lk + q * 4 + 0] = k.x; Bs[lr][lk + q * 4 + 1] = k.y;
    Bs[lr][lk + q * 4 + 2] = k.z; Bs[lr][lk + q * 4 + 3] = k.w;
  }
  __syncthreads();
  int m0 = (tid >> 4) << 2, n0 = (tid & 15) << 2;
  float acc[4][4] = {};
  for (int kk = 0; kk < 64; kk++) {
    float av[4], bv[4];
#pragma unroll
    for (int i = 0; i < 4; i++) { av[i] = As[m0 + i][kk]; bv[i] = Bs[n0 + i][kk]; }
#pragma unroll
    for (int i = 0; i < 4; i++)
#pragma unroll
      for (int j = 0; j < 4; j++) acc[i][j] = fmaf(av[i], bv[j], acc[i][j]);
  }
#pragma unroll
  for (int i = 0; i < 4; i++)
#pragma unroll
    for (int j = 0; j < 4; j++)
      S[(size_t)(s0 + m0 + i) * Ss + t0 + n0 + j] = acc[i][j] * (1.f / 16.f);
}

// ---------------- column stats pass 1: partial max/sum over 256-row chunks ----
// grid (Ss/256, 8, nz): x→col chunk, y→row chunk, z→(b_local,h)
__global__ __launch_bounds__(256) void k_colstat1(const float* __restrict__ Sc,
    float* __restrict__ pm, float* __restrict__ pl) {
  int z = blockIdx.z;
  int t = blockIdx.x * 256 + threadIdx.x;
  int rc = blockIdx.y;
  const float* S = Sc + (size_t)z * Ss * Ss + (size_t)rc * 256 * Ss + t;
  float m = -1e30f, l = 0.f;
  for (int s = 0; s < 256; s++) {
    float v = S[(size_t)s * Ss];
    float nm = fmaxf(m, v);
    l = l * __expf(m - nm) + __expf(v - nm);
    m = nm;
  }
  pm[((size_t)z * 8 + rc) * Ss + t] = m;
  pl[((size_t)z * 8 + rc) * Ss + t] = l;
}

// ---------------- column stats pass 2: combine 8 partials per column ---------
__global__ __launch_bounds__(256) void k_colstat2(const float* __restrict__ pm,
    const float* __restrict__ pl, float* __restrict__ cm, float* __restrict__ icl) {
  int idx = blockIdx.x * 256 + threadIdx.x;  // nz*Ss
  int z = idx >> 11, t = idx & 2047;
  float m = -1e30f;
#pragma unroll
  for (int rc = 0; rc < 8; rc++) m = fmaxf(m, pm[((size_t)z * 8 + rc) * Ss + t]);
  float l = 0.f;
#pragma unroll
  for (int rc = 0; rc < 8; rc++)
    l += pl[((size_t)z * 8 + rc) * Ss + t] * __expf(pm[((size_t)z * 8 + rc) * Ss + t] - m);
  cm[(size_t)z * Ss + t] = m;
  icl[(size_t)z * Ss + t] = 1.f / l;
}

// ---------------- row stats of A1 = exp(S-cm)*icl, wave per row --------------
__global__ __launch_bounds__(256) void k_rowstat(const float* __restrict__ Sc,
    const float* __restrict__ cm, const float* __restrict__ icl,
    float* __restrict__ rm, float* __restrict__ rl) {
  int wid = (blockIdx.x << 2) + (threadIdx.x >> 6);
  int lane = threadIdx.x & 63;
  int z = wid >> 11, s = wid & 2047;
  const float* row  = Sc + (size_t)z * Ss * Ss + (size_t)s * Ss;
  const float* cmz  = cm + (size_t)z * Ss;
  const float* iclz = icl + (size_t)z * Ss;
  float m = -1e30f, l = 0.f;
  for (int t0 = lane * 4; t0 < Ss; t0 += 256) {
    float4 v = *reinterpret_cast<const float4*>(row + t0);
    float4 c = *reinterpret_cast<const float4*>(cmz + t0);
    float4 ic = *reinterpret_cast<const float4*>(iclz + t0);
    float a0 = __expf(v.x - c.x) * ic.x;
    float a1 = __expf(v.y - c.y) * ic.y;
    float a2 = __expf(v.z - c.z) * ic.z;
    float a3 = __expf(v.w - c.w) * ic.w;
    float vm = fmaxf(fmaxf(a0, a1), fmaxf(a2, a3));
    float nm = fmaxf(m, vm);
    l = l * __expf(m - nm) + __expf(a0 - nm) + __expf(a1 - nm) +
        __expf(a2 - nm) + __expf(a3 - nm);
    m = nm;
  }
#pragma unroll
  for (int off = 32; off; off >>= 1) {
    float mo = __shfl_xor(m, off);
    float lo = __shfl_xor(l, off);
    float nm = fmaxf(m, mo);
    l = l * __expf(m - nm) + lo * __expf(mo - nm);
    m = nm;
  }
  if (lane == 0) {
    rm[(size_t)z * Ss + s] = m;
    rl[(size_t)z * Ss + s] = l;
  }
}

// ---------------- A2@V with fused col-normalize + row softmax ----------------
// grid (32, nz): x→s tile, y→(b_local,h)
__global__ __launch_bounds__(256) void k_av(const float* __restrict__ Sc,
    const float* __restrict__ Vf, const float* __restrict__ cm, const float* __restrict__ icl,
    const float* __restrict__ rm, const float* __restrict__ rl,
    float* __restrict__ Zall, int bStart) {
  __shared__ float As[64][65];
  __shared__ float Bs[64][65];
  int tid = threadIdx.x;
  int z = blockIdx.y;
  int b = bStart + (z >> 2), h = z & 3;
  const float* A = Sc + (size_t)z * Ss * Ss;
  const float* Vb = Vf + (size_t)b * Ss * Ee + h * Dd;
  const float* cmz  = cm + (size_t)z * Ss;
  const float* iclz = icl + (size_t)z * Ss;
  const float* rmz = rm + (size_t)z * Ss;
  const float* rlz = rl + (size_t)z * Ss;
  int s0 = blockIdx.x * 64;
  int lr = tid >> 2, lk = (tid & 3) << 4;
  float mrow = rmz[s0 + lr];
  int m0 = (tid >> 4) << 2, n0 = (tid & 15) << 2;
  float acc[4][4] = {};
  for (int k0 = 0; k0 < Ss; k0 += 64) {
#pragma unroll
    for (int q = 0; q < 4; q++) {
      int tcol = k0 + lk + q * 4;
      float4 a = *reinterpret_cast<const float4*>(A + (size_t)(s0 + lr) * Ss + tcol);
      float4 c = *reinterpret_cast<const float4*>(cmz + tcol);
      float4 ic = *reinterpret_cast<const float4*>(iclz + tcol);
      As[lr][lk + q * 4 + 0] = __expf(__expf(a.x - c.x) * ic.x - mrow);
      As[lr][lk + q * 4 + 1] = __expf(__expf(a.y - c.y) * ic.y - mrow);
      As[lr][lk + q * 4 + 2] = __expf(__expf(a.z - c.z) * ic.z - mrow);
      As[lr][lk + q * 4 + 3] = __expf(__expf(a.w - c.w) * ic.w - mrow);
      float4 v = *reinterpret_cast<const float4*>(Vb + (size_t)(k0 + lr) * Ee + lk + q * 4);
      Bs[lr][lk + q * 4 + 0] = v.x; Bs[lr][lk + q * 4 + 1] = v.y;
      Bs[lr][lk + q * 4 + 2] = v.z; Bs[lr][lk + q * 4 + 3] = v.w;
    }
    __syncthreads();
    for (int kk = 0; kk < 64; kk++) {
      float av[4], bv[4];
#pragma unroll
      for (int i = 0; i < 4; i++) { av[i] = As[m0 + i][kk]; bv[i] = Bs[kk][n0 + i]; }
#pragma unroll
      for (int i = 0; i < 4; i++)
#pragma unroll
        for (int j = 0; j < 4; j++) acc[i][j] = fmaf(av[i], bv[j], acc[i][j]);
    }
    __syncthreads();
  }
#pragma unroll
  for (int i = 0; i < 4; i++) {
    int s = s0 + m0 + i;
    float inv = 1.f / rlz[s];
#pragma unroll
    for (int j = 0; j < 4; j++)
      Zall[(size_t)(b * Ss + s) * Ee + h * Dd + n0 + j] = acc[i][j] * inv;
  }
}

// ---------------- ZF projection + residual: x += Zall@Wz^T + bz ----------------
__global__ __launch_bounds__(256) void k_zf(const float* __restrict__ Zall,
    const float* __restrict__ Wzp, const float* __restrict__ bzp,
    float* __restrict__ x, int mod) {
  __shared__ float As[16][65];
  __shared__ float Bs[16][65];
  int tid = threadIdx.x;
  int bn = blockIdx.x, bm = blockIdx.y;
  const float* W = Wzp + (size_t)mod * Ee * Ee;
  const float* bias = bzp + mod * Ee;
  int ctile = bn << 6;
  int m0 = (tid >> 4) << 2, n0 = (tid & 15) << 2;
  int lr = tid >> 2, lk = (tid & 3) << 2;
  float acc[4][4] = {};
  for (int k0 = 0; k0 < Ee; k0 += 16) {
    float4 a = *reinterpret_cast<const float4*>(Zall + (size_t)(bm * 64 + lr) * Ee + k0 + lk);
    float4 w = *reinterpret_cast<const float4*>(W + (size_t)(ctile + lr) * Ee + k0 + lk);
    As[lk + 0][lr] = a.x; As[lk + 1][lr] = a.y; As[lk + 2][lr] = a.z; As[lk + 3][lr] = a.w;
    Bs[lk + 0][lr] = w.x; Bs[lk + 1][lr] = w.y; Bs[lk + 2][lr] = w.z; Bs[lk + 3][lr] = w.w;
    __syncthreads();
#pragma unroll
    for (int kk = 0; kk < 16; kk++) {
      float av[4], bv2[4];
#pragma unroll
      for (int i = 0; i < 4; i++) { av[i] = As[kk][m0 + i]; bv2[i] = Bs[kk][n0 + i]; }
#pragma unroll
      for (int i = 0; i < 4; i++)
#pragma unroll
        for (int j = 0; j < 4; j++) acc[i][j] = fmaf(av[i], bv2[j], acc[i][j]);
    }
    __syncthreads();
  }
#pragma unroll
  for (int i = 0; i < 4; i++) {
    int gm = bm * 64 + m0 + i;
#pragma unroll
    for (int j = 0; j < 4; j++) {
      int gn = ctile + n0 + j;
      x[(size_t)gm * Ee + gn] += acc[i][j] + bias[gn];
    }
  }
}

// ---------------- final head ----------------
__global__ __launch_bounds__(256) void k_final1(const float* __restrict__ x,
    const float* __restrict__ Wo, float* __restrict__ part) {
  int c = blockIdx.x, l = blockIdx.y, b = blockIdx.z;
  int tid = threadIdx.x;
  const float4* xr = reinterpret_cast<const float4*>(x + (size_t)b * (Ss * Ee) + c * 8192);
  const float4* wr = reinterpret_cast<const float4*>(Wo + (size_t)l * (Ss * Ee) + c * 8192);
  float sum = 0.f;
  for (int i = tid; i < 2048; i += 256) {
    float4 a = xr[i], w = wr[i];
    sum += a.x * w.x + a.y * w.y + a.z * w.z + a.w * w.w;
  }
  __shared__ float red[256];
  red[tid] = sum;
  __syncthreads();
  for (int o = 128; o; o >>= 1) {
    if (tid < o) red[tid] += red[tid + o];
    __syncthreads();
  }
  if (tid == 0) part[((b * 16 + l) << 6) + c] = red[0];
}

__global__ void k_final2(const float* __restrict__ part, const float* __restrict__ bo,
                         float* __restrict__ out) {
  int idx = threadIdx.x;   // 128 = 8*16
  int b = idx >> 4, l = idx & 15;
  float s = 0.f;
  for (int c = 0; c < 64; c++) s += part[((b * 16 + l) << 6) + c];
  s += bo[l];
  out[idx] = 1.f / (1.f + __expf(-s));
}

extern "C" void kernel_launch(void* const* d_in, const int* in_sizes, int n_in,
                              void* d_out, int out_size, void* d_ws, size_t ws_size,
                              hipStream_t stream) {
  const int*   seqs = (const int*)d_in[0];
  const float* emb  = (const float*)d_in[1];
  const float* Wq   = (const float*)d_in[2];
  const float* bq   = (const float*)d_in[3];
  const float* Wk   = (const float*)d_in[4];
  const float* bk   = (const float*)d_in[5];
  const float* Wv   = (const float*)d_in[6];
  const float* bv   = (const float*)d_in[7];
  const float* Wz   = (const float*)d_in[8];
  const float* bz   = (const float*)d_in[9];
  const float* Wo   = (const float*)d_in[10];
  const float* bo   = (const float*)d_in[11];
  float* out = (float*)d_out;
  float* ws  = (float*)d_ws;

  float* x    = ws;                    // 4,194,304 floats each for x..Zall
  float* Qf   = ws + 4194304;
  float* Kf   = ws + 8388608;
  float* Vf   = ws + 12582912;
  float* Zall = ws + 16777216;
  float* part = ws + 20971520;         // 8,192
  size_t base = 20979712;

  // choose chunk size CH: need(CH) = base + CH*Hh*Ss*(4 stat arrays + 16 partials) + CH*Hh*Ss*Ss
  int CH = 1;
  for (int c = 8; c >= 1; c >>= 1) {
    if (c != 8 && c != 4 && c != 2 && c != 1) continue;
    size_t need = base + (size_t)c * Hh * Ss * 20 + (size_t)c * Hh * Ss * Ss;
    if (need * 4 <= ws_size) { CH = c; break; }
  }
  size_t statN = (size_t)CH * Hh * Ss;
  float* rm  = ws + base;
  float* rl  = rm + statN;
  float* cm  = rl + statN;
  float* icl = cm + statN;
  float* pm  = icl + statN;
  float* pl  = pm + statN * 8;
  float* Sc  = pl + statN * 8;

  k_gather<<<(Bb * Ss * 64) / 256, 256, 0, stream>>>(seqs, emb, x);

  for (int m = 0; m < 2; m++) {
    k_qkv<<<dim3(12, 256), 256, 0, stream>>>(x, Wq, Wk, Wv, bq, bk, bv, Qf, Kf, Vf, m);
    for (int b0 = 0; b0 < Bb; b0 += CH) {
      int nb = (Bb - b0 < CH) ? (Bb - b0) : CH;
      int nz = nb * Hh;
      k_scores<<<dim3(32, 32, nz), 256, 0, stream>>>(Qf, Kf, Sc, b0);
      k_colstat1<<<dim3(Ss / 256, 8, nz), 256, 0, stream>>>(Sc, pm, pl);
      k_colstat2<<<(nz * Ss) / 256, 256, 0, stream>>>(pm, pl, cm, icl);
      k_rowstat<<<(nz * Ss) / 4, 256, 0, stream>>>(Sc, cm, icl, rm, rl);
      k_av<<<dim3(32, nz), 256, 0, stream>>>(Sc, Vf, cm, icl, rm, rl, Zall, b0);
    }
    k_zf<<<dim3(4, 256), 256, 0, stream>>>(Zall, Wz, bz, x, m);
  }

  k_final1<<<dim3(64, 16, 8), 256, 0, stream>>>(x, Wo, part);
  k_final2<<<1, 128, 0, stream>>>(part, bo, out);
}

// Round 3
// 1951.912 us; speedup vs baseline: 2.2523x; 1.3698x over previous
//
#include <hip/hip_runtime.h>
#include <math.h>

#define Bb 8
#define Ss 2048
#define Ee 256
#define Hh 4
#define Dd 64
#define TC 4            // t-chunks for split-T AV

__device__ __forceinline__ unsigned short f2bf(float f) {
  union { float f; unsigned int u; } c; c.f = f;
  return (unsigned short)((c.u + 0x7FFFu + ((c.u >> 16) & 1u)) >> 16);
}
__device__ __forceinline__ float bf2f(unsigned short u) {
  union { unsigned int u; float f; } c; c.u = ((unsigned int)u) << 16;
  return c.f;
}

// ---------------- embedding gather ----------------
__global__ __launch_bounds__(256) void k_gather(const int* __restrict__ seqs,
                                                const float* __restrict__ emb,
                                                float* __restrict__ x) {
  int idx = blockIdx.x * 256 + threadIdx.x;
  int row = idx >> 6, c4 = idx & 63;
  int tok = seqs[row];
  reinterpret_cast<float4*>(x)[(size_t)row * 64 + c4] =
      reinterpret_cast<const float4*>(emb)[(size_t)tok * 64 + c4];
}

// ---------------- fused Q/K/V projection (relu(x@W^T + b)) ----------------
__global__ __launch_bounds__(256) void k_qkv(const float* __restrict__ x,
    const float* __restrict__ Wq, const float* __restrict__ Wk, const float* __restrict__ Wv,
    const float* __restrict__ bq, const float* __restrict__ bk, const float* __restrict__ bv,
    float* __restrict__ Qf, float* __restrict__ Kf, float* __restrict__ Vf, int mod) {
  __shared__ float As[16][65];
  __shared__ float Bs[16][65];
  int tid = threadIdx.x;
  int bn = blockIdx.x, bm = blockIdx.y;
  int w = bn >> 2;
  int ctile = (bn & 3) << 6;
  const float* W = (w == 0 ? Wq : (w == 1 ? Wk : Wv)) + (size_t)mod * Hh * Dd * Ee;
  const float* bias = (w == 0 ? bq : (w == 1 ? bk : bv)) + mod * Hh * Dd;
  float* Out = (w == 0 ? Qf : (w == 1 ? Kf : Vf));
  int m0 = (tid >> 4) << 2, n0 = (tid & 15) << 2;
  int lr = tid >> 2, lk = (tid & 3) << 2;
  float acc[4][4] = {};
  for (int k0 = 0; k0 < Ee; k0 += 16) {
    float4 a = *reinterpret_cast<const float4*>(x + (size_t)(bm * 64 + lr) * Ee + k0 + lk);
    float4 b = *reinterpret_cast<const float4*>(W + (size_t)(ctile + lr) * Ee + k0 + lk);
    As[lk + 0][lr] = a.x; As[lk + 1][lr] = a.y; As[lk + 2][lr] = a.z; As[lk + 3][lr] = a.w;
    Bs[lk + 0][lr] = b.x; Bs[lk + 1][lr] = b.y; Bs[lk + 2][lr] = b.z; Bs[lk + 3][lr] = b.w;
    __syncthreads();
#pragma unroll
    for (int kk = 0; kk < 16; kk++) {
      float av[4], bv2[4];
#pragma unroll
      for (int i = 0; i < 4; i++) { av[i] = As[kk][m0 + i]; bv2[i] = Bs[kk][n0 + i]; }
#pragma unroll
      for (int i = 0; i < 4; i++)
#pragma unroll
        for (int j = 0; j < 4; j++) acc[i][j] = fmaf(av[i], bv2[j], acc[i][j]);
    }
    __syncthreads();
  }
#pragma unroll
  for (int i = 0; i < 4; i++) {
    int gm = bm * 64 + m0 + i;
#pragma unroll
    for (int j = 0; j < 4; j++) {
      int c = ctile + n0 + j;
      float v = acc[i][j] + bias[c];
      Out[(size_t)gm * Ee + c] = v > 0.f ? v : 0.f;
    }
  }
}

// ---------------- scores: Sc[s,t] = bf16((Q·K)/16) per (b,h) ----------------
__global__ __launch_bounds__(256) void k_scores(const float* __restrict__ Qf,
    const float* __restrict__ Kf, unsigned short* __restrict__ Sc, int bStart) {
  __shared__ float As[64][65];
  __shared__ float Bs[64][65];
  int tid = threadIdx.x;
  int z = blockIdx.z;
  int b = bStart + (z >> 2), h = z & 3;
  const float* Qb = Qf + (size_t)b * Ss * Ee + h * Dd;
  const float* Kb = Kf + (size_t)b * Ss * Ee + h * Dd;
  unsigned short* S = Sc + (size_t)z * Ss * Ss;
  int lr = tid >> 2, lk = (tid & 3) << 4;
  int s0 = blockIdx.y * 64, t0 = blockIdx.x * 64;
#pragma unroll
  for (int q = 0; q < 4; q++) {
    float4 a = *reinterpret_cast<const float4*>(Qb + (size_t)(s0 + lr) * Ee + lk + q * 4);
    float4 k = *reinterpret_cast<const float4*>(Kb + (size_t)(t0 + lr) * Ee + lk + q * 4);
    As[lr][lk + q * 4 + 0] = a.x; As[lr][lk + q * 4 + 1] = a.y;
    As[lr][lk + q * 4 + 2] = a.z; As[lr][lk + q * 4 + 3] = a.w;
    Bs[lr][lk + q * 4 + 0] = k.x; Bs[lr][lk + q * 4 + 1] = k.y;
    Bs[lr][lk + q * 4 + 2] = k.z; Bs[lr][lk + q * 4 + 3] = k.w;
  }
  __syncthreads();
  int m0 = (tid >> 4) << 2, n0 = (tid & 15) << 2;
  float acc[4][4] = {};
  for (int kk = 0; kk < 64; kk++) {
    float av[4], bv[4];
#pragma unroll
    for (int i = 0; i < 4; i++) { av[i] = As[m0 + i][kk]; bv[i] = Bs[n0 + i][kk]; }
#pragma unroll
    for (int i = 0; i < 4; i++)
#pragma unroll
      for (int j = 0; j < 4; j++) acc[i][j] = fmaf(av[i], bv[j], acc[i][j]);
  }
#pragma unroll
  for (int i = 0; i < 4; i++) {
    ushort4 o;
    o.x = f2bf(acc[i][0] * (1.f / 16.f));
    o.y = f2bf(acc[i][1] * (1.f / 16.f));
    o.z = f2bf(acc[i][2] * (1.f / 16.f));
    o.w = f2bf(acc[i][3] * (1.f / 16.f));
    *reinterpret_cast<ushort4*>(S + (size_t)(s0 + m0 + i) * Ss + t0 + n0) = o;
  }
}

// ---------------- column stats pass 1: partial max/sum over 256-row chunks ----
__global__ __launch_bounds__(256) void k_colstat1(const unsigned short* __restrict__ Sc,
    float* __restrict__ pm, float* __restrict__ pl) {
  int z = blockIdx.z;
  int t = blockIdx.x * 256 + threadIdx.x;
  int rc = blockIdx.y;
  const unsigned short* S = Sc + (size_t)z * Ss * Ss + (size_t)rc * 256 * Ss + t;
  float m = -1e30f, l = 0.f;
  for (int s = 0; s < 256; s++) {
    float v = bf2f(S[(size_t)s * Ss]);
    float nm = fmaxf(m, v);
    l = l * __expf(m - nm) + __expf(v - nm);
    m = nm;
  }
  pm[((size_t)z * 8 + rc) * Ss + t] = m;
  pl[((size_t)z * 8 + rc) * Ss + t] = l;
}

// ---------------- column stats pass 2: combine 8 partials per column ---------
__global__ __launch_bounds__(256) void k_colstat2(const float* __restrict__ pm,
    const float* __restrict__ pl, float* __restrict__ cm, float* __restrict__ icl) {
  int idx = blockIdx.x * 256 + threadIdx.x;  // nz*Ss
  int z = idx >> 11, t = idx & 2047;
  float m = -1e30f;
#pragma unroll
  for (int rc = 0; rc < 8; rc++) m = fmaxf(m, pm[((size_t)z * 8 + rc) * Ss + t]);
  float l = 0.f;
#pragma unroll
  for (int rc = 0; rc < 8; rc++)
    l += pl[((size_t)z * 8 + rc) * Ss + t] * __expf(pm[((size_t)z * 8 + rc) * Ss + t] - m);
  cm[(size_t)z * Ss + t] = m;
  icl[(size_t)z * Ss + t] = 1.f / l;
}

// ---------------- split-T AV with fused col-normalize + unnormalized row exp --
// A1 = exp(S-cm)*icl in (0,1); A2 = exp(A1) (no max needed).
// Opart[tc] += A2 @ V ; rspart[tc] += rowsum(A2). grid (32, TC, nz)
__global__ __launch_bounds__(256) void k_avp(const unsigned short* __restrict__ Sc,
    const float* __restrict__ Vf, const float* __restrict__ cm, const float* __restrict__ icl,
    float* __restrict__ Opart, float* __restrict__ rspart, int bStart, int nz) {
  __shared__ float As[64][65];
  __shared__ float Bs[64][65];
  int tid = threadIdx.x;
  int z = blockIdx.z, tc = blockIdx.y;
  int b = bStart + (z >> 2), h = z & 3;
  const unsigned short* A = Sc + (size_t)z * Ss * Ss;
  const float* Vb = Vf + (size_t)b * Ss * Ee + h * Dd;
  const float* cmz  = cm + (size_t)z * Ss;
  const float* iclz = icl + (size_t)z * Ss;
  int s0 = blockIdx.x * 64;
  int tbase = tc * (Ss / TC);        // 512-wide t-chunk
  int lr = tid >> 2, lk = (tid & 3) << 4;
  int m0 = (tid >> 4) << 2, n0 = (tid & 15) << 2;
  float acc[4][4] = {};
  float rsum = 0.f;
  for (int k0 = 0; k0 < Ss / TC; k0 += 64) {
#pragma unroll
    for (int q = 0; q < 4; q++) {
      int tcol = tbase + k0 + lk + q * 4;
      ushort4 a = *reinterpret_cast<const ushort4*>(A + (size_t)(s0 + lr) * Ss + tcol);
      float4 c = *reinterpret_cast<const float4*>(cmz + tcol);
      float4 ic = *reinterpret_cast<const float4*>(iclz + tcol);
      float a0 = __expf(__expf(bf2f(a.x) - c.x) * ic.x);
      float a1 = __expf(__expf(bf2f(a.y) - c.y) * ic.y);
      float a2 = __expf(__expf(bf2f(a.z) - c.z) * ic.z);
      float a3 = __expf(__expf(bf2f(a.w) - c.w) * ic.w);
      As[lr][lk + q * 4 + 0] = a0; As[lr][lk + q * 4 + 1] = a1;
      As[lr][lk + q * 4 + 2] = a2; As[lr][lk + q * 4 + 3] = a3;
      rsum += a0 + a1 + a2 + a3;
      float4 v = *reinterpret_cast<const float4*>(Vb + (size_t)(tbase + k0 + lr) * Ee + lk + q * 4);
      Bs[lr][lk + q * 4 + 0] = v.x; Bs[lr][lk + q * 4 + 1] = v.y;
      Bs[lr][lk + q * 4 + 2] = v.z; Bs[lr][lk + q * 4 + 3] = v.w;
    }
    __syncthreads();
    for (int kk = 0; kk < 64; kk++) {
      float av[4], bv[4];
#pragma unroll
      for (int i = 0; i < 4; i++) { av[i] = As[m0 + i][kk]; bv[i] = Bs[kk][n0 + i]; }
#pragma unroll
      for (int i = 0; i < 4; i++)
#pragma unroll
        for (int j = 0; j < 4; j++) acc[i][j] = fmaf(av[i], bv[j], acc[i][j]);
    }
    __syncthreads();
  }
  // combine rsum across the 4 threads sharing row lr (consecutive lanes)
  rsum += __shfl_xor(rsum, 1);
  rsum += __shfl_xor(rsum, 2);
  float* P = Opart + ((size_t)(tc * nz + z) * Ss) * Dd;
  if ((tid & 3) == 0)
    rspart[(size_t)(tc * nz + z) * Ss + s0 + lr] = rsum;
#pragma unroll
  for (int i = 0; i < 4; i++) {
    float4 o; o.x = acc[i][0]; o.y = acc[i][1]; o.z = acc[i][2]; o.w = acc[i][3];
    *reinterpret_cast<float4*>(P + (size_t)(s0 + m0 + i) * Dd + n0) = o;
  }
}

// ---------------- combine split-T partials, normalize, write Zall ------------
__global__ __launch_bounds__(256) void k_avred(const float* __restrict__ Opart,
    const float* __restrict__ rspart, float* __restrict__ Zall, int bStart, int nz) {
  int e = blockIdx.x * 256 + threadIdx.x;    // nz*Ss*16 float4s
  int z = e >> 15, s = (e >> 4) & 2047, d4 = e & 15;
  float4 o = make_float4(0.f, 0.f, 0.f, 0.f);
  float rs = 0.f;
#pragma unroll
  for (int tc = 0; tc < TC; tc++) {
    const float4* P = reinterpret_cast<const float4*>(
        Opart + ((size_t)(tc * nz + z) * Ss + s) * Dd);
    float4 p = P[d4];
    o.x += p.x; o.y += p.y; o.z += p.z; o.w += p.w;
    rs += rspart[(size_t)(tc * nz + z) * Ss + s];
  }
  float inv = 1.f / rs;
  int b = bStart + (z >> 2), h = z & 3;
  float4 r; r.x = o.x * inv; r.y = o.y * inv; r.z = o.z * inv; r.w = o.w * inv;
  *reinterpret_cast<float4*>(Zall + (size_t)(b * Ss + s) * Ee + h * Dd + d4 * 4) = r;
}

// ---------------- ZF projection + residual: x += Zall@Wz^T + bz ----------------
__global__ __launch_bounds__(256) void k_zf(const float* __restrict__ Zall,
    const float* __restrict__ Wzp, const float* __restrict__ bzp,
    float* __restrict__ x, int mod) {
  __shared__ float As[16][65];
  __shared__ float Bs[16][65];
  int tid = threadIdx.x;
  int bn = blockIdx.x, bm = blockIdx.y;
  const float* W = Wzp + (size_t)mod * Ee * Ee;
  const float* bias = bzp + mod * Ee;
  int ctile = bn << 6;
  int m0 = (tid >> 4) << 2, n0 = (tid & 15) << 2;
  int lr = tid >> 2, lk = (tid & 3) << 2;
  float acc[4][4] = {};
  for (int k0 = 0; k0 < Ee; k0 += 16) {
    float4 a = *reinterpret_cast<const float4*>(Zall + (size_t)(bm * 64 + lr) * Ee + k0 + lk);
    float4 w = *reinterpret_cast<const float4*>(W + (size_t)(ctile + lr) * Ee + k0 + lk);
    As[lk + 0][lr] = a.x; As[lk + 1][lr] = a.y; As[lk + 2][lr] = a.z; As[lk + 3][lr] = a.w;
    Bs[lk + 0][lr] = w.x; Bs[lk + 1][lr] = w.y; Bs[lk + 2][lr] = w.z; Bs[lk + 3][lr] = w.w;
    __syncthreads();
#pragma unroll
    for (int kk = 0; kk < 16; kk++) {
      float av[4], bv2[4];
#pragma unroll
      for (int i = 0; i < 4; i++) { av[i] = As[kk][m0 + i]; bv2[i] = Bs[kk][n0 + i]; }
#pragma unroll
      for (int i = 0; i < 4; i++)
#pragma unroll
        for (int j = 0; j < 4; j++) acc[i][j] = fmaf(av[i], bv2[j], acc[i][j]);
    }
    __syncthreads();
  }
#pragma unroll
  for (int i = 0; i < 4; i++) {
    int gm = bm * 64 + m0 + i;
#pragma unroll
    for (int j = 0; j < 4; j++) {
      int gn = ctile + n0 + j;
      x[(size_t)gm * Ee + gn] += acc[i][j] + bias[gn];
    }
  }
}

// ---------------- final head ----------------
__global__ __launch_bounds__(256) void k_final1(const float* __restrict__ x,
    const float* __restrict__ Wo, float* __restrict__ part) {
  int c = blockIdx.x, l = blockIdx.y, b = blockIdx.z;
  int tid = threadIdx.x;
  const float4* xr = reinterpret_cast<const float4*>(x + (size_t)b * (Ss * Ee) + c * 8192);
  const float4* wr = reinterpret_cast<const float4*>(Wo + (size_t)l * (Ss * Ee) + c * 8192);
  float sum = 0.f;
  for (int i = tid; i < 2048; i += 256) {
    float4 a = xr[i], w = wr[i];
    sum += a.x * w.x + a.y * w.y + a.z * w.z + a.w * w.w;
  }
  __shared__ float red[256];
  red[tid] = sum;
  __syncthreads();
  for (int o = 128; o; o >>= 1) {
    if (tid < o) red[tid] += red[tid + o];
    __syncthreads();
  }
  if (tid == 0) part[((b * 16 + l) << 6) + c] = red[0];
}

__global__ void k_final2(const float* __restrict__ part, const float* __restrict__ bo,
                         float* __restrict__ out) {
  int idx = threadIdx.x;   // 128 = 8*16
  int b = idx >> 4, l = idx & 15;
  float s = 0.f;
  for (int c = 0; c < 64; c++) s += part[((b * 16 + l) << 6) + c];
  s += bo[l];
  out[idx] = 1.f / (1.f + __expf(-s));
}

extern "C" void kernel_launch(void* const* d_in, const int* in_sizes, int n_in,
                              void* d_out, int out_size, void* d_ws, size_t ws_size,
                              hipStream_t stream) {
  const int*   seqs = (const int*)d_in[0];
  const float* emb  = (const float*)d_in[1];
  const float* Wq   = (const float*)d_in[2];
  const float* bq   = (const float*)d_in[3];
  const float* Wk   = (const float*)d_in[4];
  const float* bk   = (const float*)d_in[5];
  const float* Wv   = (const float*)d_in[6];
  const float* bv   = (const float*)d_in[7];
  const float* Wz   = (const float*)d_in[8];
  const float* bz   = (const float*)d_in[9];
  const float* Wo   = (const float*)d_in[10];
  const float* bo   = (const float*)d_in[11];
  float* out = (float*)d_out;
  float* ws  = (float*)d_ws;

  float* x    = ws;
  float* Qf   = ws + 4194304;
  float* Kf   = ws + 8388608;
  float* Vf   = ws + 12582912;
  float* Zall = ws + 16777216;
  float* part = ws + 20971520;         // 8,192
  size_t base = 20979712;

  // need(c) = base + statN*(2 cm/icl + 16 pm/pl + 4 rspart + 256 Opart)
  //           + c*Hh*Ss*Ss/2 (bf16 Sc), statN = c*Hh*Ss
  int CH = 1;
  for (int c = 8; c >= 1; c >>= 1) {
    size_t statN = (size_t)c * Hh * Ss;
    size_t need = base + statN * 278 + (size_t)c * Hh * Ss * Ss / 2;
    if (need * 4 <= ws_size) { CH = c; break; }
  }
  size_t statN = (size_t)CH * Hh * Ss;
  float* cm     = ws + base;
  float* icl    = cm + statN;
  float* pm     = icl + statN;
  float* pl     = pm + statN * 8;
  float* rspart = pl + statN * 8;
  float* Opart  = rspart + statN * TC;
  unsigned short* Sc = reinterpret_cast<unsigned short*>(Opart + statN * TC * Dd);

  k_gather<<<(Bb * Ss * 64) / 256, 256, 0, stream>>>(seqs, emb, x);

  for (int m = 0; m < 2; m++) {
    k_qkv<<<dim3(12, 256), 256, 0, stream>>>(x, Wq, Wk, Wv, bq, bk, bv, Qf, Kf, Vf, m);
    for (int b0 = 0; b0 < Bb; b0 += CH) {
      int nb = (Bb - b0 < CH) ? (Bb - b0) : CH;
      int nz = nb * Hh;
      k_scores<<<dim3(32, 32, nz), 256, 0, stream>>>(Qf, Kf, Sc, b0);
      k_colstat1<<<dim3(Ss / 256, 8, nz), 256, 0, stream>>>(Sc, pm, pl);
      k_colstat2<<<(nz * Ss) / 256, 256, 0, stream>>>(pm, pl, cm, icl);
      k_avp<<<dim3(32, TC, nz), 256, 0, stream>>>(Sc, Vf, cm, icl, Opart, rspart, b0, nz);
      k_avred<<<(nz * Ss * 16) / 256, 256, 0, stream>>>(Opart, rspart, Zall, b0, nz);
    }
    k_zf<<<dim3(4, 256), 256, 0, stream>>>(Zall, Wz, bz, x, m);
  }

  k_final1<<<dim3(64, 16, 8), 256, 0, stream>>>(x, Wo, part);
  k_final2<<<1, 128, 0, stream>>>(part, bo, out);
}

// Round 4
// 989.301 us; speedup vs baseline: 4.4438x; 1.9730x over previous
//
#include <hip/hip_runtime.h>
#include <math.h>

#define Bb 8
#define Ss 2048
#define Ee 256
#define Hh 4
#define Dd 64
#define TC 4            // t-chunks for split-T AV
#define TS (Ss / TC)    // 512

typedef unsigned short u16;
typedef __attribute__((ext_vector_type(8))) short bf16x8;
typedef __attribute__((ext_vector_type(4))) float f32x4;

__device__ __forceinline__ u16 f2bf(float f) {
  union { float f; unsigned int u; } c; c.f = f;
  return (u16)((c.u + 0x7FFFu + ((c.u >> 16) & 1u)) >> 16);
}
__device__ __forceinline__ float bf2f(u16 u) {
  union { unsigned int u; float f; } c; c.u = ((unsigned int)u) << 16;
  return c.f;
}
__device__ __forceinline__ float bf2fs(short s) { return bf2f((u16)s); }

// ---------------- embedding gather ----------------
__global__ __launch_bounds__(256) void k_gather(const int* __restrict__ seqs,
                                                const float* __restrict__ emb,
                                                float* __restrict__ x) {
  int idx = blockIdx.x * 256 + threadIdx.x;
  int row = idx >> 6, c4 = idx & 63;
  int tok = seqs[row];
  reinterpret_cast<float4*>(x)[(size_t)row * 64 + c4] =
      reinterpret_cast<const float4*>(emb)[(size_t)tok * 64 + c4];
}

// ---------------- fused Q/K/V projection (relu(x@W^T + b)) -> bf16 ----------
__global__ __launch_bounds__(256) void k_qkv(const float* __restrict__ x,
    const float* __restrict__ Wq, const float* __restrict__ Wk, const float* __restrict__ Wv,
    const float* __restrict__ bq, const float* __restrict__ bk, const float* __restrict__ bv,
    u16* __restrict__ Qf, u16* __restrict__ Kf, u16* __restrict__ Vf, int mod) {
  __shared__ float As[16][65];
  __shared__ float Bs[16][65];
  int tid = threadIdx.x;
  int bn = blockIdx.x, bm = blockIdx.y;
  int w = bn >> 2;
  int ctile = (bn & 3) << 6;
  const float* W = (w == 0 ? Wq : (w == 1 ? Wk : Wv)) + (size_t)mod * Hh * Dd * Ee;
  const float* bias = (w == 0 ? bq : (w == 1 ? bk : bv)) + mod * Hh * Dd;
  u16* Out = (w == 0 ? Qf : (w == 1 ? Kf : Vf));
  int m0 = (tid >> 4) << 2, n0 = (tid & 15) << 2;
  int lr = tid >> 2, lk = (tid & 3) << 2;
  float acc[4][4] = {};
  for (int k0 = 0; k0 < Ee; k0 += 16) {
    float4 a = *reinterpret_cast<const float4*>(x + (size_t)(bm * 64 + lr) * Ee + k0 + lk);
    float4 b = *reinterpret_cast<const float4*>(W + (size_t)(ctile + lr) * Ee + k0 + lk);
    As[lk + 0][lr] = a.x; As[lk + 1][lr] = a.y; As[lk + 2][lr] = a.z; As[lk + 3][lr] = a.w;
    Bs[lk + 0][lr] = b.x; Bs[lk + 1][lr] = b.y; Bs[lk + 2][lr] = b.z; Bs[lk + 3][lr] = b.w;
    __syncthreads();
#pragma unroll
    for (int kk = 0; kk < 16; kk++) {
      float av[4], bv2[4];
#pragma unroll
      for (int i = 0; i < 4; i++) { av[i] = As[kk][m0 + i]; bv2[i] = Bs[kk][n0 + i]; }
#pragma unroll
      for (int i = 0; i < 4; i++)
#pragma unroll
        for (int j = 0; j < 4; j++) acc[i][j] = fmaf(av[i], bv2[j], acc[i][j]);
    }
    __syncthreads();
  }
#pragma unroll
  for (int i = 0; i < 4; i++) {
    int gm = bm * 64 + m0 + i;
#pragma unroll
    for (int j = 0; j < 4; j++) {
      int c = ctile + n0 + j;
      float v = acc[i][j] + bias[c];
      Out[(size_t)gm * Ee + c] = f2bf(v > 0.f ? v : 0.f);
    }
  }
}

// ---------------- V transpose: Vf[b][t][h*64+d] -> Vt[(b*4+h)*64+d][t] -------
__global__ __launch_bounds__(256) void k_vt(const u16* __restrict__ Vf,
                                            u16* __restrict__ Vt) {
  __shared__ u16 T[64][72];
  int tid = threadIdx.x;
  int t0 = blockIdx.x * 64;
  int z = blockIdx.y;           // global (b*4+h), 0..31
  int b = z >> 2, h = z & 3;
  int lr = tid >> 2, lc = (tid & 3) << 4;
#pragma unroll
  for (int hh = 0; hh < 2; hh++) {
    bf16x8 v = *reinterpret_cast<const bf16x8*>(
        Vf + (size_t)(b * Ss + t0 + lr) * Ee + h * Dd + lc + hh * 8);
#pragma unroll
    for (int j = 0; j < 8; j++) T[lr][lc + hh * 8 + j] = (u16)v[j];
  }
  __syncthreads();
#pragma unroll
  for (int j = 0; j < 16; j++) {
    Vt[((size_t)z * Dd + lr) * Ss + t0 + lc + j] = T[lc + j][lr];
  }
}

// ---------------- SV[z][d] = sum_t Vt[z*64+d][t] -----------------------------
__global__ __launch_bounds__(256) void k_vsum(const u16* __restrict__ Vt,
                                              float* __restrict__ SV) {
  int z = blockIdx.y;
  int d = blockIdx.x * 4 + (threadIdx.x >> 6);
  int lane = threadIdx.x & 63;
  const u16* row = Vt + ((size_t)z * Dd + d) * Ss;
  float s = 0.f;
#pragma unroll
  for (int it = 0; it < 4; it++) {
    bf16x8 v = *reinterpret_cast<const bf16x8*>(row + it * 512 + lane * 8);
#pragma unroll
    for (int j = 0; j < 8; j++) s += bf2fs(v[j]);
  }
#pragma unroll
  for (int off = 32; off; off >>= 1) s += __shfl_xor(s, off);
  if (lane == 0) SV[(size_t)z * Dd + d] = s;
}

// ---------------- scores (MFMA bf16): Sc[s,t] = bf16((Q·K)/16) ---------------
// block: 128x128 output tile; grid (16, 16, nz)
__global__ __launch_bounds__(256) void k_scores(const u16* __restrict__ Qf,
    const u16* __restrict__ Kf, u16* __restrict__ Sc, int bStart) {
  __shared__ short Qs[128][72];
  __shared__ short Ks[128][72];
  int tid = threadIdx.x;
  int z = blockIdx.z;
  int b = bStart + (z >> 2), h = z & 3;
  const u16* Qb = Qf + (size_t)b * Ss * Ee + h * Dd;
  const u16* Kb = Kf + (size_t)b * Ss * Ee + h * Dd;
  u16* S = Sc + (size_t)z * Ss * Ss;
  int s0 = blockIdx.y * 128, t0 = blockIdx.x * 128;
  // stage: 2 threads per row, 32 cols each
  int lr = tid >> 1, lc = (tid & 1) << 5;
#pragma unroll
  for (int hh = 0; hh < 4; hh++) {
    *reinterpret_cast<bf16x8*>(&Qs[lr][lc + hh * 8]) =
        *reinterpret_cast<const bf16x8*>(Qb + (size_t)(s0 + lr) * Ee + lc + hh * 8);
    *reinterpret_cast<bf16x8*>(&Ks[lr][lc + hh * 8]) =
        *reinterpret_cast<const bf16x8*>(Kb + (size_t)(t0 + lr) * Ee + lc + hh * 8);
  }
  __syncthreads();
  int w = tid >> 6, lane = tid & 63;
  int ml = lane & 15, q = lane >> 4;
  int sh = (w >> 1) << 6, th = (w & 1) << 6;
  f32x4 acc[4][4] = {};
#pragma unroll
  for (int ks = 0; ks < 2; ks++) {
    bf16x8 af[4], bf[4];
#pragma unroll
    for (int mt = 0; mt < 4; mt++)
      af[mt] = *reinterpret_cast<const bf16x8*>(&Qs[sh + mt * 16 + ml][ks * 32 + q * 8]);
#pragma unroll
    for (int nt = 0; nt < 4; nt++)
      bf[nt] = *reinterpret_cast<const bf16x8*>(&Ks[th + nt * 16 + ml][ks * 32 + q * 8]);
#pragma unroll
    for (int mt = 0; mt < 4; mt++)
#pragma unroll
      for (int nt = 0; nt < 4; nt++)
        acc[mt][nt] = __builtin_amdgcn_mfma_f32_16x16x32_bf16(af[mt], bf[nt], acc[mt][nt], 0, 0, 0);
  }
#pragma unroll
  for (int mt = 0; mt < 4; mt++)
#pragma unroll
    for (int nt = 0; nt < 4; nt++)
#pragma unroll
      for (int r = 0; r < 4; r++) {
        int row = s0 + sh + mt * 16 + q * 4 + r;
        int col = t0 + th + nt * 16 + ml;
        S[(size_t)row * Ss + col] = f2bf(acc[mt][nt][r] * (1.f / 16.f));
      }
}

// ---------------- column stats pass 1 ----------------------------------------
__global__ __launch_bounds__(256) void k_colstat1(const u16* __restrict__ Sc,
    float* __restrict__ pm, float* __restrict__ pl) {
  int z = blockIdx.z;
  int t = blockIdx.x * 256 + threadIdx.x;
  int rc = blockIdx.y;
  const u16* S = Sc + (size_t)z * Ss * Ss + (size_t)rc * 256 * Ss + t;
  float m = -1e30f, l = 0.f;
  for (int s = 0; s < 256; s++) {
    float v = bf2f(S[(size_t)s * Ss]);
    float nm = fmaxf(m, v);
    l = l * __expf(m - nm) + __expf(v - nm);
    m = nm;
  }
  pm[((size_t)z * 8 + rc) * Ss + t] = m;
  pl[((size_t)z * 8 + rc) * Ss + t] = l;
}

// ---------------- column stats pass 2 ----------------------------------------
__global__ __launch_bounds__(256) void k_colstat2(const float* __restrict__ pm,
    const float* __restrict__ pl, float* __restrict__ cm, float* __restrict__ icl) {
  int idx = blockIdx.x * 256 + threadIdx.x;  // nz*Ss
  int z = idx >> 11, t = idx & 2047;
  float m = -1e30f;
#pragma unroll
  for (int rc = 0; rc < 8; rc++) m = fmaxf(m, pm[((size_t)z * 8 + rc) * Ss + t]);
  float l = 0.f;
#pragma unroll
  for (int rc = 0; rc < 8; rc++)
    l += pl[((size_t)z * 8 + rc) * Ss + t] * __expf(pm[((size_t)z * 8 + rc) * Ss + t] - m);
  cm[(size_t)z * Ss + t] = m;
  icl[(size_t)z * Ss + t] = 1.f / l;
}

// ---------------- AV (MFMA bf16): Opart = A2' @ V, rspart = rowsum(A2') ------
// A1 = exp(S-cm)*icl in (0,1); A2' = exp(A1)-1 (bf16-safe, keeps signal).
// grid (32, TC, nz); block 64x64 output tile
__global__ __launch_bounds__(256) void k_avp(const u16* __restrict__ Sc,
    const u16* __restrict__ Vt, const float* __restrict__ cm, const float* __restrict__ icl,
    float* __restrict__ Opart, float* __restrict__ rspart, int bStart, int nz) {
  __shared__ short A2s[64][72];
  __shared__ short Vs[64][72];
  int tid = threadIdx.x;
  int z = blockIdx.z, tc = blockIdx.y;
  int zg = bStart * Hh + z;
  const u16* A = Sc + (size_t)z * Ss * Ss;
  const u16* VtZ = Vt + (size_t)zg * Dd * Ss;
  const float* cmz  = cm + (size_t)z * Ss;
  const float* iclz = icl + (size_t)z * Ss;
  int s0 = blockIdx.x * 64;
  int tbase = tc * TS;
  int lr = tid >> 2, lcq = (tid & 3) << 4;
  int w = tid >> 6, lane = tid & 63;
  int ml = lane & 15, q = lane >> 4;
  f32x4 acc[4] = {};
  float rsum = 0.f;
  for (int k0 = 0; k0 < TS; k0 += 64) {
#pragma unroll
    for (int hh = 0; hh < 2; hh++) {
      int col = lcq + hh * 8;
      int tcol = tbase + k0 + col;
      bf16x8 a = *reinterpret_cast<const bf16x8*>(A + (size_t)(s0 + lr) * Ss + tcol);
      float4 c0 = *reinterpret_cast<const float4*>(cmz + tcol);
      float4 c1 = *reinterpret_cast<const float4*>(cmz + tcol + 4);
      float4 i0 = *reinterpret_cast<const float4*>(iclz + tcol);
      float4 i1 = *reinterpret_cast<const float4*>(iclz + tcol + 4);
      float cv[8] = {c0.x, c0.y, c0.z, c0.w, c1.x, c1.y, c1.z, c1.w};
      float iv[8] = {i0.x, i0.y, i0.z, i0.w, i1.x, i1.y, i1.z, i1.w};
      bf16x8 o;
#pragma unroll
      for (int j = 0; j < 8; j++) {
        float a1 = __expf(bf2fs(a[j]) - cv[j]) * iv[j];
        float a2p = __expf(a1) - 1.f;
        rsum += a2p;
        o[j] = (short)f2bf(a2p);
      }
      *reinterpret_cast<bf16x8*>(&A2s[lr][col]) = o;
      // V stage: row lr is d here
      *reinterpret_cast<bf16x8*>(&Vs[lr][col]) =
          *reinterpret_cast<const bf16x8*>(VtZ + (size_t)lr * Ss + tcol);
    }
    __syncthreads();
#pragma unroll
    for (int ks = 0; ks < 2; ks++) {
      bf16x8 af = *reinterpret_cast<const bf16x8*>(&A2s[(w << 4) + ml][ks * 32 + q * 8]);
#pragma unroll
      for (int nt = 0; nt < 4; nt++) {
        bf16x8 bfr = *reinterpret_cast<const bf16x8*>(&Vs[nt * 16 + ml][ks * 32 + q * 8]);
        acc[nt] = __builtin_amdgcn_mfma_f32_16x16x32_bf16(af, bfr, acc[nt], 0, 0, 0);
      }
    }
    __syncthreads();
  }
  rsum += __shfl_xor(rsum, 1);
  rsum += __shfl_xor(rsum, 2);
  size_t pbase = (size_t)(tc * nz + z) * Ss;
  if ((tid & 3) == 0) rspart[pbase + s0 + lr] = rsum;
#pragma unroll
  for (int nt = 0; nt < 4; nt++)
#pragma unroll
    for (int r = 0; r < 4; r++) {
      int s = s0 + (w << 4) + q * 4 + r;
      Opart[(pbase + s) * Dd + nt * 16 + ml] = acc[nt][r];
    }
}

// ---------------- combine split-T partials + SV, normalize, write Zall -------
__global__ __launch_bounds__(256) void k_avred(const float* __restrict__ Opart,
    const float* __restrict__ rspart, const float* __restrict__ SV,
    float* __restrict__ Zall, int bStart, int nz) {
  int e = blockIdx.x * 256 + threadIdx.x;    // nz*Ss*16 float4s
  int z = e >> 15, s = (e >> 4) & 2047, d4 = e & 15;
  int zg = bStart * Hh + z;
  float4 sv = *reinterpret_cast<const float4*>(SV + (size_t)zg * Dd + d4 * 4);
  float4 o = sv;
  float rs = (float)Ss;
#pragma unroll
  for (int tc = 0; tc < TC; tc++) {
    const float4* P = reinterpret_cast<const float4*>(
        Opart + ((size_t)(tc * nz + z) * Ss + s) * Dd);
    float4 p = P[d4];
    o.x += p.x; o.y += p.y; o.z += p.z; o.w += p.w;
    rs += rspart[(size_t)(tc * nz + z) * Ss + s];
  }
  float inv = 1.f / rs;
  int b = bStart + (z >> 2), h = z & 3;
  float4 r; r.x = o.x * inv; r.y = o.y * inv; r.z = o.z * inv; r.w = o.w * inv;
  *reinterpret_cast<float4*>(Zall + (size_t)(b * Ss + s) * Ee + h * Dd + d4 * 4) = r;
}

// ---------------- ZF projection + residual: x += Zall@Wz^T + bz --------------
__global__ __launch_bounds__(256) void k_zf(const float* __restrict__ Zall,
    const float* __restrict__ Wzp, const float* __restrict__ bzp,
    float* __restrict__ x, int mod) {
  __shared__ float As[16][65];
  __shared__ float Bs[16][65];
  int tid = threadIdx.x;
  int bn = blockIdx.x, bm = blockIdx.y;
  const float* W = Wzp + (size_t)mod * Ee * Ee;
  const float* bias = bzp + mod * Ee;
  int ctile = bn << 6;
  int m0 = (tid >> 4) << 2, n0 = (tid & 15) << 2;
  int lr = tid >> 2, lk = (tid & 3) << 2;
  float acc[4][4] = {};
  for (int k0 = 0; k0 < Ee; k0 += 16) {
    float4 a = *reinterpret_cast<const float4*>(Zall + (size_t)(bm * 64 + lr) * Ee + k0 + lk);
    float4 w = *reinterpret_cast<const float4*>(W + (size_t)(ctile + lr) * Ee + k0 + lk);
    As[lk + 0][lr] = a.x; As[lk + 1][lr] = a.y; As[lk + 2][lr] = a.z; As[lk + 3][lr] = a.w;
    Bs[lk + 0][lr] = w.x; Bs[lk + 1][lr] = w.y; Bs[lk + 2][lr] = w.z; Bs[lk + 3][lr] = w.w;
    __syncthreads();
#pragma unroll
    for (int kk = 0; kk < 16; kk++) {
      float av[4], bv2[4];
#pragma unroll
      for (int i = 0; i < 4; i++) { av[i] = As[kk][m0 + i]; bv2[i] = Bs[kk][n0 + i]; }
#pragma unroll
      for (int i = 0; i < 4; i++)
#pragma unroll
        for (int j = 0; j < 4; j++) acc[i][j] = fmaf(av[i], bv2[j], acc[i][j]);
    }
    __syncthreads();
  }
#pragma unroll
  for (int i = 0; i < 4; i++) {
    int gm = bm * 64 + m0 + i;
#pragma unroll
    for (int j = 0; j < 4; j++) {
      int gn = ctile + n0 + j;
      x[(size_t)gm * Ee + gn] += acc[i][j] + bias[gn];
    }
  }
}

// ---------------- final head ----------------
__global__ __launch_bounds__(256) void k_final1(const float* __restrict__ x,
    const float* __restrict__ Wo, float* __restrict__ part) {
  int c = blockIdx.x, l = blockIdx.y, b = blockIdx.z;
  int tid = threadIdx.x;
  const float4* xr = reinterpret_cast<const float4*>(x + (size_t)b * (Ss * Ee) + c * 8192);
  const float4* wr = reinterpret_cast<const float4*>(Wo + (size_t)l * (Ss * Ee) + c * 8192);
  float sum = 0.f;
  for (int i = tid; i < 2048; i += 256) {
    float4 a = xr[i], w = wr[i];
    sum += a.x * w.x + a.y * w.y + a.z * w.z + a.w * w.w;
  }
  __shared__ float red[256];
  red[tid] = sum;
  __syncthreads();
  for (int o = 128; o; o >>= 1) {
    if (tid < o) red[tid] += red[tid + o];
    __syncthreads();
  }
  if (tid == 0) part[((b * 16 + l) << 6) + c] = red[0];
}

__global__ void k_final2(const float* __restrict__ part, const float* __restrict__ bo,
                         float* __restrict__ out) {
  int idx = threadIdx.x;   // 128 = 8*16
  int b = idx >> 4, l = idx & 15;
  float s = 0.f;
  for (int c = 0; c < 64; c++) s += part[((b * 16 + l) << 6) + c];
  s += bo[l];
  out[idx] = 1.f / (1.f + __expf(-s));
}

extern "C" void kernel_launch(void* const* d_in, const int* in_sizes, int n_in,
                              void* d_out, int out_size, void* d_ws, size_t ws_size,
                              hipStream_t stream) {
  const int*   seqs = (const int*)d_in[0];
  const float* emb  = (const float*)d_in[1];
  const float* Wq   = (const float*)d_in[2];
  const float* bq   = (const float*)d_in[3];
  const float* Wk   = (const float*)d_in[4];
  const float* bk   = (const float*)d_in[5];
  const float* Wv   = (const float*)d_in[6];
  const float* bv   = (const float*)d_in[7];
  const float* Wz   = (const float*)d_in[8];
  const float* bz   = (const float*)d_in[9];
  const float* Wo   = (const float*)d_in[10];
  const float* bo   = (const float*)d_in[11];
  float* out = (float*)d_out;
  float* ws  = (float*)d_ws;

  float* x    = ws;                                    // 4,194,304 f
  u16*   Qf   = (u16*)(ws + 4194304);                  // 2,097,152 f-equiv
  u16*   Kf   = (u16*)(ws + 6291456);
  u16*   Vf   = (u16*)(ws + 8388608);
  u16*   Vt   = (u16*)(ws + 10485760);
  float* Zall = ws + 12582912;                         // 4,194,304 f
  float* SV   = ws + 16777216;                         // 2,048 f
  float* part = ws + 16779264;                         // 8,192 f
  size_t base = 16787456;

  // chunk region: cm+icl (2) + pm+pl (16) + rspart (4) + Opart (256) + Sc (1024) = 1302*statN
  int CH = 1;
  for (int c = 8; c >= 1; c >>= 1) {
    size_t statN = (size_t)c * Hh * Ss;
    size_t need = base + statN * 1302;
    if (need * 4 <= ws_size) { CH = c; break; }
  }
  size_t statN = (size_t)CH * Hh * Ss;
  float* cm     = ws + base;
  float* icl    = cm + statN;
  float* pm     = icl + statN;
  float* pl     = pm + statN * 8;
  float* rspart = pl + statN * 8;
  float* Opart  = rspart + statN * TC;
  u16*   Sc     = (u16*)(Opart + statN * TC * Dd);

  k_gather<<<(Bb * Ss * 64) / 256, 256, 0, stream>>>(seqs, emb, x);

  for (int m = 0; m < 2; m++) {
    k_qkv<<<dim3(12, 256), 256, 0, stream>>>(x, Wq, Wk, Wv, bq, bk, bv, Qf, Kf, Vf, m);
    k_vt<<<dim3(32, 32), 256, 0, stream>>>(Vf, Vt);
    k_vsum<<<dim3(16, 32), 256, 0, stream>>>(Vt, SV);
    for (int b0 = 0; b0 < Bb; b0 += CH) {
      int nb = (Bb - b0 < CH) ? (Bb - b0) : CH;
      int nz = nb * Hh;
      k_scores<<<dim3(16, 16, nz), 256, 0, stream>>>(Qf, Kf, Sc, b0);
      k_colstat1<<<dim3(Ss / 256, 8, nz), 256, 0, stream>>>(Sc, pm, pl);
      k_colstat2<<<(nz * Ss) / 256, 256, 0, stream>>>(pm, pl, cm, icl);
      k_avp<<<dim3(32, TC, nz), 256, 0, stream>>>(Sc, Vt, cm, icl, Opart, rspart, b0, nz);
      k_avred<<<(nz * Ss * 16) / 256, 256, 0, stream>>>(Opart, rspart, SV, Zall, b0, nz);
    }
    k_zf<<<dim3(4, 256), 256, 0, stream>>>(Zall, Wz, bz, x, m);
  }

  k_final1<<<dim3(64, 16, 8), 256, 0, stream>>>(x, Wo, part);
  k_final2<<<1, 128, 0, stream>>>(part, bo, out);
}

// Round 5
// 713.286 us; speedup vs baseline: 6.1633x; 1.3870x over previous
//
#include <hip/hip_runtime.h>
#include <math.h>

#define Bb 8
#define Ss 2048
#define Ee 256
#define Hh 4
#define Dd 64
#define TC 4            // t-chunks for split-T AV
#define TS (Ss / TC)    // 512

typedef unsigned short u16;
typedef __attribute__((ext_vector_type(8))) short bf16x8;
typedef __attribute__((ext_vector_type(4))) float f32x4;

__device__ __forceinline__ u16 f2bf(float f) {
  union { float f; unsigned int u; } c; c.f = f;
  return (u16)((c.u + 0x7FFFu + ((c.u >> 16) & 1u)) >> 16);
}
__device__ __forceinline__ float bf2f(u16 u) {
  union { unsigned int u; float f; } c; c.u = ((unsigned int)u) << 16;
  return c.f;
}
__device__ __forceinline__ float bf2fs(short s) { return bf2f((u16)s); }

// ---------------- weight fp32 -> bf16 convert ----------------
__global__ __launch_bounds__(256) void k_w2b(const float* __restrict__ src,
                                             u16* __restrict__ dst) {
  int idx = (blockIdx.x * 256 + threadIdx.x) * 4;
  float4 v = *reinterpret_cast<const float4*>(src + idx);
  ushort4 o;
  o.x = f2bf(v.x); o.y = f2bf(v.y); o.z = f2bf(v.z); o.w = f2bf(v.w);
  *reinterpret_cast<ushort4*>(dst + idx) = o;
}

// ---------------- embedding gather (fp32 x + bf16 xb) ----------------
__global__ __launch_bounds__(256) void k_gather(const int* __restrict__ seqs,
                                                const float* __restrict__ emb,
                                                float* __restrict__ x,
                                                u16* __restrict__ xb) {
  int idx = blockIdx.x * 256 + threadIdx.x;
  int row = idx >> 6, c4 = idx & 63;
  int tok = seqs[row];
  float4 v = reinterpret_cast<const float4*>(emb)[(size_t)tok * 64 + c4];
  reinterpret_cast<float4*>(x)[(size_t)row * 64 + c4] = v;
  ushort4 o;
  o.x = f2bf(v.x); o.y = f2bf(v.y); o.z = f2bf(v.z); o.w = f2bf(v.w);
  reinterpret_cast<ushort4*>(xb)[(size_t)row * 64 + c4] = o;
}

// ---------------- QKV projection (MFMA bf16): relu(xb@W^T+b) -> bf16 --------
// grid (6, 128): bn>>1 selects {q,k,v}; (bn&1)*128 col tile; 128 row tiles
__global__ __launch_bounds__(256) void k_qkvm(const u16* __restrict__ xb,
    const u16* __restrict__ Wqb, const u16* __restrict__ Wkb, const u16* __restrict__ Wvb,
    const float* __restrict__ bq, const float* __restrict__ bk, const float* __restrict__ bv,
    u16* __restrict__ Qf, u16* __restrict__ Kf, u16* __restrict__ Vf, int mod) {
  __shared__ short Xs[128][72];
  __shared__ short Ws[128][72];
  int tid = threadIdx.x;
  int bn = blockIdx.x;
  int arr = bn >> 1, coff = (bn & 1) << 7;
  const u16* W = (arr == 0 ? Wqb : arr == 1 ? Wkb : Wvb) + (size_t)mod * 256 * 256;
  const float* bias = (arr == 0 ? bq : arr == 1 ? bk : bv) + mod * 256;
  u16* Out = (arr == 0 ? Qf : arr == 1 ? Kf : Vf);
  int s0 = blockIdx.y * 128;
  int lr = tid >> 1, lc = (tid & 1) << 5;
  int w = tid >> 6, lane = tid & 63, ml = lane & 15, q = lane >> 4;
  int sh = (w >> 1) << 6, th = (w & 1) << 6;
  f32x4 acc[4][4] = {};
  for (int k0 = 0; k0 < 256; k0 += 64) {
#pragma unroll
    for (int hh = 0; hh < 4; hh++) {
      *reinterpret_cast<bf16x8*>(&Xs[lr][lc + hh * 8]) =
          *reinterpret_cast<const bf16x8*>(xb + (size_t)(s0 + lr) * Ee + k0 + lc + hh * 8);
      *reinterpret_cast<bf16x8*>(&Ws[lr][lc + hh * 8]) =
          *reinterpret_cast<const bf16x8*>(W + (size_t)(coff + lr) * Ee + k0 + lc + hh * 8);
    }
    __syncthreads();
#pragma unroll
    for (int ks = 0; ks < 2; ks++) {
      bf16x8 af[4], bfr[4];
#pragma unroll
      for (int mt = 0; mt < 4; mt++)
        af[mt] = *reinterpret_cast<const bf16x8*>(&Xs[sh + mt * 16 + ml][ks * 32 + q * 8]);
#pragma unroll
      for (int nt = 0; nt < 4; nt++)
        bfr[nt] = *reinterpret_cast<const bf16x8*>(&Ws[th + nt * 16 + ml][ks * 32 + q * 8]);
#pragma unroll
      for (int mt = 0; mt < 4; mt++)
#pragma unroll
        for (int nt = 0; nt < 4; nt++)
          acc[mt][nt] = __builtin_amdgcn_mfma_f32_16x16x32_bf16(af[mt], bfr[nt], acc[mt][nt], 0, 0, 0);
    }
    __syncthreads();
  }
#pragma unroll
  for (int mt = 0; mt < 4; mt++)
#pragma unroll
    for (int nt = 0; nt < 4; nt++)
#pragma unroll
      for (int r = 0; r < 4; r++) {
        int gm = s0 + sh + mt * 16 + q * 4 + r;
        int cc = coff + th + nt * 16 + ml;
        float v = acc[mt][nt][r] + bias[cc];
        Out[(size_t)gm * Ee + cc] = f2bf(v > 0.f ? v : 0.f);
      }
}

// ---------------- V transpose: Vf[b][t][h*64+d] -> Vt[(b*4+h)*64+d][t] -------
__global__ __launch_bounds__(256) void k_vt(const u16* __restrict__ Vf,
                                            u16* __restrict__ Vt) {
  __shared__ u16 T[64][72];
  int tid = threadIdx.x;
  int t0 = blockIdx.x * 64;
  int z = blockIdx.y;
  int b = z >> 2, h = z & 3;
  int lr = tid >> 2, lc = (tid & 3) << 4;
#pragma unroll
  for (int hh = 0; hh < 2; hh++) {
    bf16x8 v = *reinterpret_cast<const bf16x8*>(
        Vf + (size_t)(b * Ss + t0 + lr) * Ee + h * Dd + lc + hh * 8);
#pragma unroll
    for (int j = 0; j < 8; j++) T[lr][lc + hh * 8 + j] = (u16)v[j];
  }
  __syncthreads();
#pragma unroll
  for (int j = 0; j < 16; j++) {
    Vt[((size_t)z * Dd + lr) * Ss + t0 + lc + j] = T[lc + j][lr];
  }
}

// ---------------- SV[z][d] = sum_t Vt[z*64+d][t] -----------------------------
__global__ __launch_bounds__(256) void k_vsum(const u16* __restrict__ Vt,
                                              float* __restrict__ SV) {
  int z = blockIdx.y;
  int d = blockIdx.x * 4 + (threadIdx.x >> 6);
  int lane = threadIdx.x & 63;
  const u16* row = Vt + ((size_t)z * Dd + d) * Ss;
  float s = 0.f;
#pragma unroll
  for (int it = 0; it < 4; it++) {
    bf16x8 v = *reinterpret_cast<const bf16x8*>(row + it * 512 + lane * 8);
#pragma unroll
    for (int j = 0; j < 8; j++) s += bf2fs(v[j]);
  }
#pragma unroll
  for (int off = 32; off; off >>= 1) s += __shfl_xor(s, off);
  if (lane == 0) SV[(size_t)z * Dd + d] = s;
}

// ---------------- scores (MFMA bf16) + fused per-tile column stats -----------
// block: 128x128 tile; grid (16, 16, nz). Emits Sc bf16 + pm/pl[16 row-tiles]
__global__ __launch_bounds__(256) void k_scores(const u16* __restrict__ Qf,
    const u16* __restrict__ Kf, u16* __restrict__ Sc,
    float* __restrict__ pm, float* __restrict__ pl, int bStart) {
  __shared__ short Qs[128][72];
  __shared__ short Ks[128][72];
  __shared__ float smm[4][64];
  __shared__ float sml[4][64];
  int tid = threadIdx.x;
  int z = blockIdx.z;
  int b = bStart + (z >> 2), h = z & 3;
  const u16* Qb = Qf + (size_t)b * Ss * Ee + h * Dd;
  const u16* Kb = Kf + (size_t)b * Ss * Ee + h * Dd;
  u16* S = Sc + (size_t)z * Ss * Ss;
  int s0 = blockIdx.y * 128, t0 = blockIdx.x * 128;
  int lr = tid >> 1, lc = (tid & 1) << 5;
#pragma unroll
  for (int hh = 0; hh < 2; hh++) {
    *reinterpret_cast<bf16x8*>(&Qs[lr][lc + hh * 8]) =
        *reinterpret_cast<const bf16x8*>(Qb + (size_t)(s0 + lr) * Ee + lc + hh * 8);
    *reinterpret_cast<bf16x8*>(&Qs[lr][lc + 16 + hh * 8]) =
        *reinterpret_cast<const bf16x8*>(Qb + (size_t)(s0 + lr) * Ee + lc + 16 + hh * 8);
    *reinterpret_cast<bf16x8*>(&Ks[lr][lc + hh * 8]) =
        *reinterpret_cast<const bf16x8*>(Kb + (size_t)(t0 + lr) * Ee + lc + hh * 8);
    *reinterpret_cast<bf16x8*>(&Ks[lr][lc + 16 + hh * 8]) =
        *reinterpret_cast<const bf16x8*>(Kb + (size_t)(t0 + lr) * Ee + lc + 16 + hh * 8);
  }
  __syncthreads();
  int w = tid >> 6, lane = tid & 63;
  int ml = lane & 15, q = lane >> 4;
  int sh = (w >> 1) << 6, th = (w & 1) << 6;
  f32x4 acc[4][4] = {};
#pragma unroll
  for (int ks = 0; ks < 2; ks++) {
    bf16x8 af[4], bf[4];
#pragma unroll
    for (int mt = 0; mt < 4; mt++)
      af[mt] = *reinterpret_cast<const bf16x8*>(&Qs[sh + mt * 16 + ml][ks * 32 + q * 8]);
#pragma unroll
    for (int nt = 0; nt < 4; nt++)
      bf[nt] = *reinterpret_cast<const bf16x8*>(&Ks[th + nt * 16 + ml][ks * 32 + q * 8]);
#pragma unroll
    for (int mt = 0; mt < 4; mt++)
#pragma unroll
      for (int nt = 0; nt < 4; nt++)
        acc[mt][nt] = __builtin_amdgcn_mfma_f32_16x16x32_bf16(af[mt], bf[nt], acc[mt][nt], 0, 0, 0);
  }
  // write quantized scores and collect per-column (within-tile) stats
  u16 qv[4][4][4];
#pragma unroll
  for (int mt = 0; mt < 4; mt++)
#pragma unroll
    for (int nt = 0; nt < 4; nt++)
#pragma unroll
      for (int r = 0; r < 4; r++) {
        int row = s0 + sh + mt * 16 + q * 4 + r;
        int col = t0 + th + nt * 16 + ml;
        u16 u = f2bf(acc[mt][nt][r] * (1.f / 16.f));
        qv[mt][nt][r] = u;
        S[(size_t)row * Ss + col] = u;
      }
#pragma unroll
  for (int nt = 0; nt < 4; nt++) {
    float m = -1e30f, l = 0.f;
#pragma unroll
    for (int mt = 0; mt < 4; mt++)
#pragma unroll
      for (int r = 0; r < 4; r++) {
        float v = bf2f(qv[mt][nt][r]);
        float nm = fmaxf(m, v);
        l = l * __expf(m - nm) + __expf(v - nm);
        m = nm;
      }
    // butterfly over q (rows within this wave's 64-row half)
#pragma unroll
    for (int off = 16; off <= 32; off <<= 1) {
      float mo = __shfl_xor(m, off);
      float lo = __shfl_xor(l, off);
      float nm = fmaxf(m, mo);
      l = l * __expf(m - nm) + lo * __expf(mo - nm);
      m = nm;
    }
    smm[w][nt * 16 + ml] = m;
    sml[w][nt * 16 + ml] = l;
  }
  __syncthreads();
  if (tid < 128) {
    int half = tid >> 6, col = tid & 63;
    float m0 = smm[half][col], m2 = smm[half + 2][col];
    float l0 = sml[half][col], l2 = sml[half + 2][col];
    float m = fmaxf(m0, m2);
    float l = l0 * __expf(m0 - m) + l2 * __expf(m2 - m);
    int t = t0 + (half << 6) + col;
    pm[((size_t)z * 16 + blockIdx.y) * Ss + t] = m;
    pl[((size_t)z * 16 + blockIdx.y) * Ss + t] = l;
  }
}

// ---------------- column stats combine: 16 partials per column ---------------
__global__ __launch_bounds__(256) void k_colstat2(const float* __restrict__ pm,
    const float* __restrict__ pl, float* __restrict__ cm, float* __restrict__ icl) {
  int idx = blockIdx.x * 256 + threadIdx.x;  // nz*Ss
  int z = idx >> 11, t = idx & 2047;
  float m = -1e30f;
#pragma unroll
  for (int rc = 0; rc < 16; rc++) m = fmaxf(m, pm[((size_t)z * 16 + rc) * Ss + t]);
  float l = 0.f;
#pragma unroll
  for (int rc = 0; rc < 16; rc++)
    l += pl[((size_t)z * 16 + rc) * Ss + t] * __expf(pm[((size_t)z * 16 + rc) * Ss + t] - m);
  cm[(size_t)z * Ss + t] = m;
  icl[(size_t)z * Ss + t] = 1.f / l;
}

// ---------------- AV (MFMA bf16): Opart = A2' @ V, rspart = rowsum(A2') ------
// A1 = exp(S-cm)*icl in (0,1); A2' = exp(A1)-1 (bf16-safe, keeps signal).
// grid (32, TC, nz); block 64x64 output tile
__global__ __launch_bounds__(256) void k_avp(const u16* __restrict__ Sc,
    const u16* __restrict__ Vt, const float* __restrict__ cm, const float* __restrict__ icl,
    float* __restrict__ Opart, float* __restrict__ rspart, int bStart, int nz) {
  __shared__ short A2s[64][72];
  __shared__ short Vs[64][72];
  int tid = threadIdx.x;
  int z = blockIdx.z, tc = blockIdx.y;
  int zg = bStart * Hh + z;
  const u16* A = Sc + (size_t)z * Ss * Ss;
  const u16* VtZ = Vt + (size_t)zg * Dd * Ss;
  const float* cmz  = cm + (size_t)z * Ss;
  const float* iclz = icl + (size_t)z * Ss;
  int s0 = blockIdx.x * 64;
  int tbase = tc * TS;
  int lr = tid >> 2, lcq = (tid & 3) << 4;
  int w = tid >> 6, lane = tid & 63;
  int ml = lane & 15, q = lane >> 4;
  f32x4 acc[4] = {};
  float rsum = 0.f;
  for (int k0 = 0; k0 < TS; k0 += 64) {
#pragma unroll
    for (int hh = 0; hh < 2; hh++) {
      int col = lcq + hh * 8;
      int tcol = tbase + k0 + col;
      bf16x8 a = *reinterpret_cast<const bf16x8*>(A + (size_t)(s0 + lr) * Ss + tcol);
      float4 c0 = *reinterpret_cast<const float4*>(cmz + tcol);
      float4 c1 = *reinterpret_cast<const float4*>(cmz + tcol + 4);
      float4 i0 = *reinterpret_cast<const float4*>(iclz + tcol);
      float4 i1 = *reinterpret_cast<const float4*>(iclz + tcol + 4);
      float cv[8] = {c0.x, c0.y, c0.z, c0.w, c1.x, c1.y, c1.z, c1.w};
      float iv[8] = {i0.x, i0.y, i0.z, i0.w, i1.x, i1.y, i1.z, i1.w};
      bf16x8 o;
#pragma unroll
      for (int j = 0; j < 8; j++) {
        float a1 = __expf(bf2fs(a[j]) - cv[j]) * iv[j];
        float a2p = __expf(a1) - 1.f;
        rsum += a2p;
        o[j] = (short)f2bf(a2p);
      }
      *reinterpret_cast<bf16x8*>(&A2s[lr][col]) = o;
      *reinterpret_cast<bf16x8*>(&Vs[lr][col]) =
          *reinterpret_cast<const bf16x8*>(VtZ + (size_t)lr * Ss + tcol);
    }
    __syncthreads();
#pragma unroll
    for (int ks = 0; ks < 2; ks++) {
      bf16x8 af = *reinterpret_cast<const bf16x8*>(&A2s[(w << 4) + ml][ks * 32 + q * 8]);
#pragma unroll
      for (int nt = 0; nt < 4; nt++) {
        bf16x8 bfr = *reinterpret_cast<const bf16x8*>(&Vs[nt * 16 + ml][ks * 32 + q * 8]);
        acc[nt] = __builtin_amdgcn_mfma_f32_16x16x32_bf16(af, bfr, acc[nt], 0, 0, 0);
      }
    }
    __syncthreads();
  }
  rsum += __shfl_xor(rsum, 1);
  rsum += __shfl_xor(rsum, 2);
  size_t pbase = (size_t)(tc * nz + z) * Ss;
  if ((tid & 3) == 0) rspart[pbase + s0 + lr] = rsum;
#pragma unroll
  for (int nt = 0; nt < 4; nt++)
#pragma unroll
    for (int r = 0; r < 4; r++) {
      int s = s0 + (w << 4) + q * 4 + r;
      Opart[(pbase + s) * Dd + nt * 16 + ml] = acc[nt][r];
    }
}

// ---------------- combine split-T partials + SV, normalize, write Zb bf16 ----
__global__ __launch_bounds__(256) void k_avred(const float* __restrict__ Opart,
    const float* __restrict__ rspart, const float* __restrict__ SV,
    u16* __restrict__ Zb, int bStart, int nz) {
  int e = blockIdx.x * 256 + threadIdx.x;    // nz*Ss*16 float4s
  int z = e >> 15, s = (e >> 4) & 2047, d4 = e & 15;
  int zg = bStart * Hh + z;
  float4 sv = *reinterpret_cast<const float4*>(SV + (size_t)zg * Dd + d4 * 4);
  float4 o = sv;
  float rs = (float)Ss;
#pragma unroll
  for (int tc = 0; tc < TC; tc++) {
    const float4* P = reinterpret_cast<const float4*>(
        Opart + ((size_t)(tc * nz + z) * Ss + s) * Dd);
    float4 p = P[d4];
    o.x += p.x; o.y += p.y; o.z += p.z; o.w += p.w;
    rs += rspart[(size_t)(tc * nz + z) * Ss + s];
  }
  float inv = 1.f / rs;
  int b = bStart + (z >> 2), h = z & 3;
  ushort4 r;
  r.x = f2bf(o.x * inv); r.y = f2bf(o.y * inv);
  r.z = f2bf(o.z * inv); r.w = f2bf(o.w * inv);
  *reinterpret_cast<ushort4*>(Zb + (size_t)(b * Ss + s) * Ee + h * Dd + d4 * 4) = r;
}

// ---------------- ZF (MFMA bf16) + residual: x += Zb@Wz^T + bz; xb refresh ---
// grid (2, 128)
__global__ __launch_bounds__(256) void k_zfm(const u16* __restrict__ Zb,
    const u16* __restrict__ Wzb, const float* __restrict__ bzp,
    float* __restrict__ x, u16* __restrict__ xb, int mod) {
  __shared__ short Zs[128][72];
  __shared__ short Ws[128][72];
  int tid = threadIdx.x;
  int coff = blockIdx.x << 7;
  const u16* W = Wzb + (size_t)mod * 256 * 256;
  const float* bias = bzp + mod * Ee;
  int s0 = blockIdx.y * 128;
  int lr = tid >> 1, lc = (tid & 1) << 5;
  int w = tid >> 6, lane = tid & 63, ml = lane & 15, q = lane >> 4;
  int sh = (w >> 1) << 6, th = (w & 1) << 6;
  f32x4 acc[4][4] = {};
  for (int k0 = 0; k0 < 256; k0 += 64) {
#pragma unroll
    for (int hh = 0; hh < 4; hh++) {
      *reinterpret_cast<bf16x8*>(&Zs[lr][lc + hh * 8]) =
          *reinterpret_cast<const bf16x8*>(Zb + (size_t)(s0 + lr) * Ee + k0 + lc + hh * 8);
      *reinterpret_cast<bf16x8*>(&Ws[lr][lc + hh * 8]) =
          *reinterpret_cast<const bf16x8*>(W + (size_t)(coff + lr) * Ee + k0 + lc + hh * 8);
    }
    __syncthreads();
#pragma unroll
    for (int ks = 0; ks < 2; ks++) {
      bf16x8 af[4], bfr[4];
#pragma unroll
      for (int mt = 0; mt < 4; mt++)
        af[mt] = *reinterpret_cast<const bf16x8*>(&Zs[sh + mt * 16 + ml][ks * 32 + q * 8]);
#pragma unroll
      for (int nt = 0; nt < 4; nt++)
        bfr[nt] = *reinterpret_cast<const bf16x8*>(&Ws[th + nt * 16 + ml][ks * 32 + q * 8]);
#pragma unroll
      for (int mt = 0; mt < 4; mt++)
#pragma unroll
        for (int nt = 0; nt < 4; nt++)
          acc[mt][nt] = __builtin_amdgcn_mfma_f32_16x16x32_bf16(af[mt], bfr[nt], acc[mt][nt], 0, 0, 0);
    }
    __syncthreads();
  }
#pragma unroll
  for (int mt = 0; mt < 4; mt++)
#pragma unroll
    for (int nt = 0; nt < 4; nt++)
#pragma unroll
      for (int r = 0; r < 4; r++) {
        int gm = s0 + sh + mt * 16 + q * 4 + r;
        int gn = coff + th + nt * 16 + ml;
        float xv = x[(size_t)gm * Ee + gn] + acc[mt][nt][r] + bias[gn];
        x[(size_t)gm * Ee + gn] = xv;
        xb[(size_t)gm * Ee + gn] = f2bf(xv);
      }
}

// ---------------- final head ----------------
__global__ __launch_bounds__(256) void k_final1(const float* __restrict__ x,
    const float* __restrict__ Wo, float* __restrict__ part) {
  int c = blockIdx.x, l = blockIdx.y, b = blockIdx.z;
  int tid = threadIdx.x;
  const float4* xr = reinterpret_cast<const float4*>(x + (size_t)b * (Ss * Ee) + c * 8192);
  const float4* wr = reinterpret_cast<const float4*>(Wo + (size_t)l * (Ss * Ee) + c * 8192);
  float sum = 0.f;
  for (int i = tid; i < 2048; i += 256) {
    float4 a = xr[i], w = wr[i];
    sum += a.x * w.x + a.y * w.y + a.z * w.z + a.w * w.w;
  }
  __shared__ float red[256];
  red[tid] = sum;
  __syncthreads();
  for (int o = 128; o; o >>= 1) {
    if (tid < o) red[tid] += red[tid + o];
    __syncthreads();
  }
  if (tid == 0) part[((b * 16 + l) << 6) + c] = red[0];
}

__global__ void k_final2(const float* __restrict__ part, const float* __restrict__ bo,
                         float* __restrict__ out) {
  int idx = threadIdx.x;   // 128 = 8*16
  int b = idx >> 4, l = idx & 15;
  float s = 0.f;
  for (int c = 0; c < 64; c++) s += part[((b * 16 + l) << 6) + c];
  s += bo[l];
  out[idx] = 1.f / (1.f + __expf(-s));
}

extern "C" void kernel_launch(void* const* d_in, const int* in_sizes, int n_in,
                              void* d_out, int out_size, void* d_ws, size_t ws_size,
                              hipStream_t stream) {
  const int*   seqs = (const int*)d_in[0];
  const float* emb  = (const float*)d_in[1];
  const float* Wq   = (const float*)d_in[2];
  const float* bq   = (const float*)d_in[3];
  const float* Wk   = (const float*)d_in[4];
  const float* bk   = (const float*)d_in[5];
  const float* Wv   = (const float*)d_in[6];
  const float* bv   = (const float*)d_in[7];
  const float* Wz   = (const float*)d_in[8];
  const float* bz   = (const float*)d_in[9];
  const float* Wo   = (const float*)d_in[10];
  const float* bo   = (const float*)d_in[11];
  float* out = (float*)d_out;
  float* ws  = (float*)d_ws;

  float* x    = ws;                                    // 4,194,304 f
  u16*   xb   = (u16*)(ws + 4194304);                  // 2,097,152 f-equiv
  u16*   Qf   = (u16*)(ws + 6291456);
  u16*   Kf   = (u16*)(ws + 8388608);
  u16*   Vf   = (u16*)(ws + 10485760);
  u16*   Vt   = (u16*)(ws + 12582912);
  u16*   Zb   = (u16*)(ws + 14680064);
  float* SV   = ws + 16777216;                         // 2,048 f
  float* part = ws + 16779264;                         // 8,192 f
  u16*   Wqb  = (u16*)(ws + 16787456);                 // 65,536 f each
  u16*   Wkb  = (u16*)(ws + 16852992);
  u16*   Wvb  = (u16*)(ws + 16918528);
  u16*   Wzb  = (u16*)(ws + 16984064);
  size_t base = 17049600;

  // chunk region per statN: cm 1 + icl 1 + pm 16 + pl 16 + rspart 4 + Opart 256 + Sc 1024
  int CH = 1;
  for (int c = 8; c >= 1; c >>= 1) {
    size_t statN = (size_t)c * Hh * Ss;
    size_t need = base + statN * 1318;
    if (need * 4 <= ws_size) { CH = c; break; }
  }
  size_t statN = (size_t)CH * Hh * Ss;
  float* cm     = ws + base;
  float* icl    = cm + statN;
  float* pm     = icl + statN;
  float* pl     = pm + statN * 16;
  float* rspart = pl + statN * 16;
  float* Opart  = rspart + statN * TC;
  u16*   Sc     = (u16*)(Opart + statN * TC * Dd);

  k_gather<<<(Bb * Ss * 64) / 256, 256, 0, stream>>>(seqs, emb, x, xb);
  k_w2b<<<131072 / 1024, 256, 0, stream>>>(Wq, Wqb);
  k_w2b<<<131072 / 1024, 256, 0, stream>>>(Wk, Wkb);
  k_w2b<<<131072 / 1024, 256, 0, stream>>>(Wv, Wvb);
  k_w2b<<<131072 / 1024, 256, 0, stream>>>(Wz, Wzb);

  for (int m = 0; m < 2; m++) {
    k_qkvm<<<dim3(6, 128), 256, 0, stream>>>(xb, Wqb, Wkb, Wvb, bq, bk, bv, Qf, Kf, Vf, m);
    k_vt<<<dim3(32, 32), 256, 0, stream>>>(Vf, Vt);
    k_vsum<<<dim3(16, 32), 256, 0, stream>>>(Vt, SV);
    for (int b0 = 0; b0 < Bb; b0 += CH) {
      int nb = (Bb - b0 < CH) ? (Bb - b0) : CH;
      int nz = nb * Hh;
      k_scores<<<dim3(16, 16, nz), 256, 0, stream>>>(Qf, Kf, Sc, pm, pl, b0);
      k_colstat2<<<(nz * Ss) / 256, 256, 0, stream>>>(pm, pl, cm, icl);
      k_avp<<<dim3(32, TC, nz), 256, 0, stream>>>(Sc, Vt, cm, icl, Opart, rspart, b0, nz);
      k_avred<<<(nz * Ss * 16) / 256, 256, 0, stream>>>(Opart, rspart, SV, Zb, b0, nz);
    }
    k_zfm<<<dim3(2, 128), 256, 0, stream>>>(Zb, Wzb, bz, x, xb, m);
  }

  k_final1<<<dim3(64, 16, 8), 256, 0, stream>>>(x, Wo, part);
  k_final2<<<1, 128, 0, stream>>>(part, bo, out);
}